// Round 1
// baseline (807.227 us; speedup 1.0000x reference)
//
#include <hip/hip_runtime.h>
#include <hip/hip_bf16.h>

#define BS 4
#define NQ 6000
#define NV 13294
#define NH 8
#define HD 32
#define EMB 256

__device__ __constant__ int LVL_H[4]     = {100, 50, 25, 13};
__device__ __constant__ int LVL_W[4]     = {100, 50, 25, 13};
__device__ __constant__ int LVL_START[4] = {0, 10000, 12500, 13125};

// ---------------------------------------------------------------------------
// K1: v = value @ W_val + b_val, stored bf16 in [b, h, nv, 32] layout
// ---------------------------------------------------------------------------
__global__ __launch_bounds__(256) void vproj_kernel(
    const float* __restrict__ value, const float* __restrict__ W_val,
    const float* __restrict__ b_val, __hip_bfloat16* __restrict__ vbh) {
  constexpr int ROWS = 16;
  __shared__ float ldsA[ROWS * EMB];
  const int row0 = blockIdx.x * ROWS;
  const int c = threadIdx.x;

  for (int idx = threadIdx.x; idx < ROWS * 64; idx += 256) {
    int r = idx >> 6, k4 = idx & 63;
    int row = row0 + r;
    float4 v = make_float4(0.f, 0.f, 0.f, 0.f);
    if (row < BS * NV) v = *(const float4*)(value + (size_t)row * EMB + k4 * 4);
    *(float4*)(ldsA + r * EMB + k4 * 4) = v;
  }
  __syncthreads();

  float acc[ROWS];
#pragma unroll
  for (int r = 0; r < ROWS; r++) acc[r] = 0.f;

  for (int k4 = 0; k4 < 64; k4++) {
    float w0 = W_val[(4 * k4 + 0) * EMB + c];
    float w1 = W_val[(4 * k4 + 1) * EMB + c];
    float w2 = W_val[(4 * k4 + 2) * EMB + c];
    float w3 = W_val[(4 * k4 + 3) * EMB + c];
#pragma unroll
    for (int r = 0; r < ROWS; r++) {
      float4 a = *(const float4*)(ldsA + r * EMB + k4 * 4);
      acc[r] += a.x * w0 + a.y * w1 + a.z * w2 + a.w * w3;
    }
  }

  const float bias = b_val[c];
  const int h = c >> 5, d = c & 31;
#pragma unroll
  for (int r = 0; r < ROWS; r++) {
    int row = row0 + r;
    if (row < BS * NV) {
      int b = row / NV, n = row - b * NV;
      vbh[(((size_t)(b * NH + h)) * NV + n) * HD + d] =
          __float2bfloat16(acc[r] + bias);
    }
  }
}

// ---------------------------------------------------------------------------
// K2: offsets + attention-weight projection, fused softmax, pixel coords out.
// threads 0..255: offset channels; 256..383: attn channels.
// ---------------------------------------------------------------------------
__global__ __launch_bounds__(384) void qproj_kernel(
    const float* __restrict__ query, const float* __restrict__ refpts,
    const float* __restrict__ W_off, const float* __restrict__ b_off,
    const float* __restrict__ W_attn, const float* __restrict__ b_attn,
    float* __restrict__ locbuf, float* __restrict__ awbuf) {
  constexpr int ROWS = 8;
  __shared__ float ldsA[ROWS * EMB];
  const int row0 = blockIdx.x * ROWS;
  const int tid = threadIdx.x;

  for (int idx = tid; idx < ROWS * 64; idx += 384) {
    int r = idx >> 6, k4 = idx & 63;
    *(float4*)(ldsA + r * EMB + k4 * 4) =
        *(const float4*)(query + (size_t)(row0 + r) * EMB + k4 * 4);
  }
  __syncthreads();

  const bool is_off = tid < 256;
  const int c = is_off ? tid : tid - 256;
  const float* Wp = is_off ? (W_off + c) : (W_attn + c);
  const int stride = is_off ? 256 : 128;

  float acc[ROWS];
#pragma unroll
  for (int r = 0; r < ROWS; r++) acc[r] = 0.f;

  for (int k4 = 0; k4 < 64; k4++) {
    float w0 = Wp[(4 * k4 + 0) * stride];
    float w1 = Wp[(4 * k4 + 1) * stride];
    float w2 = Wp[(4 * k4 + 2) * stride];
    float w3 = Wp[(4 * k4 + 3) * stride];
#pragma unroll
    for (int r = 0; r < ROWS; r++) {
      float4 a = *(const float4*)(ldsA + r * EMB + k4 * 4);
      acc[r] += a.x * w0 + a.y * w1 + a.z * w2 + a.w * w3;
    }
  }

  if (is_off) {
    // c = ((h*4 + l)*4 + p)*2 + xy
    const int xy = c & 1, l = (c >> 3) & 3;
    const float dim = (xy == 0) ? (float)LVL_W[l] : (float)LVL_H[l];
    const float bias = b_off[c];
#pragma unroll
    for (int r = 0; r < ROWS; r++) {
      int row = row0 + r;  // row == b*NQ + q, matches refpts flat layout
      float ref = refpts[((size_t)row * 4 + l) * 2 + xy];
      // pixel coord: loc*Dim - 0.5 with loc = ref + off/Dim  ==> ref*Dim+off-0.5
      locbuf[(size_t)row * 256 + c] = ref * dim + (acc[r] + bias) - 0.5f;
    }
  } else {
    const float bias = b_attn[c];
#pragma unroll
    for (int r = 0; r < ROWS; r++) {
      float v = acc[r] + bias;
      float m = v;
      m = fmaxf(m, __shfl_xor(m, 1));
      m = fmaxf(m, __shfl_xor(m, 2));
      m = fmaxf(m, __shfl_xor(m, 4));
      m = fmaxf(m, __shfl_xor(m, 8));
      float e = __expf(v - m);
      float s = e;
      s += __shfl_xor(s, 1);
      s += __shfl_xor(s, 2);
      s += __shfl_xor(s, 4);
      s += __shfl_xor(s, 8);
      awbuf[(size_t)(row0 + r) * 128 + c] = e / s;
    }
  }
}

// ---------------------------------------------------------------------------
// K3: bilinear sampling + weighted sum. One wave per (b,q,h);
// 64 lanes = 2 samples x 32 dims, 8 iterations over the 16 (l,p) samples.
// ---------------------------------------------------------------------------
__global__ __launch_bounds__(256) void sample_kernel(
    const __hip_bfloat16* __restrict__ vbh, const float* __restrict__ locbuf,
    const float* __restrict__ awbuf, float* __restrict__ sampled) {
  const int wid = (blockIdx.x * 256 + threadIdx.x) >> 6;
  const int lane = threadIdx.x & 63;
  if (wid >= BS * NQ * NH) return;
  const int h = wid & 7;
  const int row = wid >> 3;  // b*NQ + q
  const int b = row / NQ;
  const __hip_bfloat16* vb = vbh + ((size_t)(b * NH + h)) * NV * HD;
  const int half = lane >> 5;
  const int d = lane & 31;

  float acc = 0.f;
#pragma unroll
  for (int it = 0; it < 8; ++it) {
    const int s = it * 2 + half;  // 0..15 ; l = s>>2, p = s&3
    const int l = s >> 2;
    const float sx = locbuf[(size_t)row * 256 + (h * 16 + s) * 2 + 0];
    const float sy = locbuf[(size_t)row * 256 + (h * 16 + s) * 2 + 1];
    const float w = awbuf[(size_t)row * 128 + h * 16 + s];

    const int W_ = LVL_W[l], H_ = LVL_H[l];
    const float fx = floorf(sx), fy = floorf(sy);
    const int x0 = (int)fx, y0 = (int)fy;
    const float wx1 = sx - fx, wy1 = sy - fy;
    const float wx0 = 1.f - wx1, wy0 = 1.f - wy1;
    const bool xv0 = (x0 >= 0) & (x0 < W_);
    const bool xv1 = (x0 + 1 >= 0) & (x0 + 1 < W_);
    const bool yv0 = (y0 >= 0) & (y0 < H_);
    const bool yv1 = (y0 + 1 >= 0) & (y0 + 1 < H_);
    const __hip_bfloat16* base = vb + (size_t)LVL_START[l] * HD + d;

    float v00 = (xv0 && yv0) ? (float)base[(size_t)(y0 * W_ + x0) * HD] : 0.f;
    float v01 = (xv1 && yv0) ? (float)base[(size_t)(y0 * W_ + x0 + 1) * HD] : 0.f;
    float v10 = (xv0 && yv1) ? (float)base[(size_t)((y0 + 1) * W_ + x0) * HD] : 0.f;
    float v11 = (xv1 && yv1) ? (float)base[(size_t)((y0 + 1) * W_ + x0 + 1) * HD] : 0.f;

    acc += w * (wy0 * (wx0 * v00 + wx1 * v01) + wy1 * (wx0 * v10 + wx1 * v11));
  }
  acc += __shfl_xor(acc, 32);
  if (half == 0) sampled[(size_t)row * EMB + h * HD + d] = acc;
}

// ---------------------------------------------------------------------------
// K4: out = sampled @ W_out + b_out + query  (residual fused)
// ---------------------------------------------------------------------------
__global__ __launch_bounds__(256) void oproj_kernel(
    const float* __restrict__ sampled, const float* __restrict__ W_out,
    const float* __restrict__ b_out, const float* __restrict__ query,
    float* __restrict__ out) {
  constexpr int ROWS = 16;
  __shared__ float ldsA[ROWS * EMB];
  const int row0 = blockIdx.x * ROWS;
  const int c = threadIdx.x;

  for (int idx = threadIdx.x; idx < ROWS * 64; idx += 256) {
    int r = idx >> 6, k4 = idx & 63;
    *(float4*)(ldsA + r * EMB + k4 * 4) =
        *(const float4*)(sampled + (size_t)(row0 + r) * EMB + k4 * 4);
  }
  __syncthreads();

  float acc[ROWS];
#pragma unroll
  for (int r = 0; r < ROWS; r++) acc[r] = 0.f;

  for (int k4 = 0; k4 < 64; k4++) {
    float w0 = W_out[(4 * k4 + 0) * EMB + c];
    float w1 = W_out[(4 * k4 + 1) * EMB + c];
    float w2 = W_out[(4 * k4 + 2) * EMB + c];
    float w3 = W_out[(4 * k4 + 3) * EMB + c];
#pragma unroll
    for (int r = 0; r < ROWS; r++) {
      float4 a = *(const float4*)(ldsA + r * EMB + k4 * 4);
      acc[r] += a.x * w0 + a.y * w1 + a.z * w2 + a.w * w3;
    }
  }

  const float bias = b_out[c];
#pragma unroll
  for (int r = 0; r < ROWS; r++) {
    size_t row = row0 + r;
    out[row * EMB + c] = acc[r] + bias + query[row * EMB + c];
  }
}

// ---------------------------------------------------------------------------
extern "C" void kernel_launch(void* const* d_in, const int* in_sizes, int n_in,
                              void* d_out, int out_size, void* d_ws,
                              size_t ws_size, hipStream_t stream) {
  const float* query  = (const float*)d_in[0];
  const float* value  = (const float*)d_in[1];
  const float* refpts = (const float*)d_in[2];
  const float* W_off  = (const float*)d_in[3];
  const float* b_off  = (const float*)d_in[4];
  const float* W_attn = (const float*)d_in[5];
  const float* b_attn = (const float*)d_in[6];
  const float* W_val  = (const float*)d_in[7];
  const float* b_val  = (const float*)d_in[8];
  const float* W_out  = (const float*)d_in[9];
  const float* b_out  = (const float*)d_in[10];
  float* out = (float*)d_out;

  char* ws = (char*)d_ws;
  __hip_bfloat16* vbh = (__hip_bfloat16*)ws;              // 27,226,112 B
  float* locbuf = (float*)(ws + 27226112);                // 24,576,000 B
  float* awbuf  = (float*)(ws + 27226112 + 24576000);     // 12,288,000 B
  float* sampled = (float*)(ws + 27226112 + 24576000 + 12288000);  // 24,576,000 B

  // K1: value projection (53176 rows, 16 rows/block)
  vproj_kernel<<<(BS * NV + 15) / 16, 256, 0, stream>>>(value, W_val, b_val, vbh);
  // K2: offset/attn projection + softmax (24000 rows, 8 rows/block)
  qproj_kernel<<<BS * NQ / 8, 384, 0, stream>>>(query, refpts, W_off, b_off,
                                                W_attn, b_attn, locbuf, awbuf);
  // K3: sampling (one wave per (b,q,h))
  sample_kernel<<<BS * NQ * NH / 4, 256, 0, stream>>>(vbh, locbuf, awbuf, sampled);
  // K4: output projection + residual
  oproj_kernel<<<BS * NQ / 16, 256, 0, stream>>>(sampled, W_out, b_out, query, out);
}

// Round 2
// 542.299 us; speedup vs baseline: 1.4885x; 1.4885x over previous
//
#include <hip/hip_runtime.h>
#include <hip/hip_bf16.h>

#define BS 4
#define NQ 6000
#define NV 13294
#define NH 8
#define HD 32
#define EMB 256

__device__ __constant__ int LVL_W[4] = {100, 50, 25, 13};
__device__ __constant__ int LVL_H[4] = {100, 50, 25, 13};

__device__ inline unsigned short bf16bits(float f) {
  __hip_bfloat16 h = __float2bfloat16(f);
  return *reinterpret_cast<unsigned short*>(&h);
}
__device__ inline float bflo(unsigned int u) { return __uint_as_float(u << 16); }
__device__ inline float bfhi(unsigned int u) { return __uint_as_float(u & 0xffff0000u); }

// ---------------------------------------------------------------------------
// K1: v = value @ W_val + b_val -> bf16 [b, h, nv, 32].
// 4x4 register blocking: thread (rq, c4) computes rows rq*4..+3, cols 4*c4..+3.
// LDS A-read is wave-uniform (broadcast); 1 ds_read_b128 feeds 16 FMAs.
// ---------------------------------------------------------------------------
__global__ __launch_bounds__(256) void vproj_kernel(
    const float* __restrict__ value, const float* __restrict__ W_val,
    const float* __restrict__ b_val, __hip_bfloat16* __restrict__ vbh) {
  constexpr int ROWS = 16;
  __shared__ float ldsA[ROWS * EMB];
  const int row0 = blockIdx.x * ROWS;
  const int tid = threadIdx.x;
  const int rq = tid >> 6;   // row quarter (0..3) -> wave-uniform
  const int c4 = tid & 63;   // col group: cols 4*c4..4*c4+3

  for (int idx = tid; idx < ROWS * 64; idx += 256) {
    int r = idx >> 6, k4 = idx & 63;
    int row = row0 + r;
    float4 v = make_float4(0.f, 0.f, 0.f, 0.f);
    if (row < BS * NV) v = *(const float4*)(value + (size_t)row * EMB + k4 * 4);
    *(float4*)(ldsA + r * EMB + k4 * 4) = v;
  }
  __syncthreads();

  float4 acc[4];
#pragma unroll
  for (int r = 0; r < 4; r++) acc[r] = make_float4(0.f, 0.f, 0.f, 0.f);

  const float* ldsBase = ldsA + rq * 4 * EMB;
  const float* Wb = W_val + 4 * c4;
  for (int k4 = 0; k4 < 64; ++k4) {
    float4 w0 = *(const float4*)(Wb + (4 * k4 + 0) * EMB);
    float4 w1 = *(const float4*)(Wb + (4 * k4 + 1) * EMB);
    float4 w2 = *(const float4*)(Wb + (4 * k4 + 2) * EMB);
    float4 w3 = *(const float4*)(Wb + (4 * k4 + 3) * EMB);
#pragma unroll
    for (int r = 0; r < 4; ++r) {
      float4 a = *(const float4*)(ldsBase + r * EMB + k4 * 4);
      acc[r].x += a.x * w0.x + a.y * w1.x + a.z * w2.x + a.w * w3.x;
      acc[r].y += a.x * w0.y + a.y * w1.y + a.z * w2.y + a.w * w3.y;
      acc[r].z += a.x * w0.z + a.y * w1.z + a.z * w2.z + a.w * w3.z;
      acc[r].w += a.x * w0.w + a.y * w1.w + a.z * w2.w + a.w * w3.w;
    }
  }

  const float4 bias = *(const float4*)(b_val + 4 * c4);
  const int h = (4 * c4) >> 5, d = (4 * c4) & 31;
#pragma unroll
  for (int r = 0; r < 4; ++r) {
    int row = row0 + rq * 4 + r;
    if (row < BS * NV) {
      int b = row / NV, n = row - b * NV;
      ushort4 u;
      u.x = bf16bits(acc[r].x + bias.x);
      u.y = bf16bits(acc[r].y + bias.y);
      u.z = bf16bits(acc[r].z + bias.z);
      u.w = bf16bits(acc[r].w + bias.w);
      *(ushort4*)(vbh + (((size_t)(b * NH + h)) * NV + n) * HD + d) = u;
    }
  }
}

// ---------------------------------------------------------------------------
// K2: offsets + attn projection, fused softmax, pixel coords out.
// 384 threads: cg = tid%96 (cg<64: offset col-quads; else attn col-quads),
// rq = tid/96 row quarter. 4 rows x 4 cols per thread.
// ---------------------------------------------------------------------------
__global__ __launch_bounds__(384) void qproj_kernel(
    const float* __restrict__ query, const float* __restrict__ refpts,
    const float* __restrict__ W_off, const float* __restrict__ b_off,
    const float* __restrict__ W_attn, const float* __restrict__ b_attn,
    float* __restrict__ locbuf, float* __restrict__ awbuf) {
  constexpr int ROWS = 16;
  __shared__ float ldsA[ROWS * EMB];
  const int row0 = blockIdx.x * ROWS;
  const int tid = threadIdx.x;
  const int cg = tid % 96;
  const int rq = tid / 96;

  for (int idx = tid; idx < ROWS * 64; idx += 384) {
    int r = idx >> 6, k4 = idx & 63;
    *(float4*)(ldsA + r * EMB + k4 * 4) =
        *(const float4*)(query + (size_t)(row0 + r) * EMB + k4 * 4);
  }
  __syncthreads();

  const bool is_off = cg < 64;
  const int c0 = is_off ? 4 * cg : 4 * (cg - 64);
  const float* Wb = is_off ? (W_off + c0) : (W_attn + c0);
  const int stride = is_off ? 256 : 128;

  float4 acc[4];
#pragma unroll
  for (int r = 0; r < 4; r++) acc[r] = make_float4(0.f, 0.f, 0.f, 0.f);

  const float* ldsBase = ldsA + rq * 4 * EMB;
  for (int k4 = 0; k4 < 64; ++k4) {
    float4 w0 = *(const float4*)(Wb + (4 * k4 + 0) * stride);
    float4 w1 = *(const float4*)(Wb + (4 * k4 + 1) * stride);
    float4 w2 = *(const float4*)(Wb + (4 * k4 + 2) * stride);
    float4 w3 = *(const float4*)(Wb + (4 * k4 + 3) * stride);
#pragma unroll
    for (int r = 0; r < 4; ++r) {
      float4 a = *(const float4*)(ldsBase + r * EMB + k4 * 4);
      acc[r].x += a.x * w0.x + a.y * w1.x + a.z * w2.x + a.w * w3.x;
      acc[r].y += a.x * w0.y + a.y * w1.y + a.z * w2.y + a.w * w3.y;
      acc[r].z += a.x * w0.z + a.y * w1.z + a.z * w2.z + a.w * w3.z;
      acc[r].w += a.x * w0.w + a.y * w1.w + a.z * w2.w + a.w * w3.w;
    }
  }

  if (is_off) {
    // cols c0..c0+3: xy = 0,1,0,1 ; same level l for all four
    const int l = (c0 >> 3) & 3;
    const float Wd = (float)LVL_W[l], Hd = (float)LVL_H[l];
    const float4 bias = *(const float4*)(b_off + c0);
#pragma unroll
    for (int r = 0; r < 4; ++r) {
      int row = row0 + rq * 4 + r;
      float2 ref = *(const float2*)(refpts + ((size_t)row * 4 + l) * 2);
      float4 o;
      o.x = ref.x * Wd + acc[r].x + bias.x - 0.5f;
      o.y = ref.y * Hd + acc[r].y + bias.y - 0.5f;
      o.z = ref.x * Wd + acc[r].z + bias.z - 0.5f;
      o.w = ref.y * Hd + acc[r].w + bias.w - 0.5f;
      *(float4*)(locbuf + (size_t)row * 256 + c0) = o;
    }
  } else {
    const float4 bias = *(const float4*)(b_attn + c0);
#pragma unroll
    for (int r = 0; r < 4; ++r) {
      float v0 = acc[r].x + bias.x, v1 = acc[r].y + bias.y;
      float v2 = acc[r].z + bias.z, v3 = acc[r].w + bias.w;
      float m = fmaxf(fmaxf(v0, v1), fmaxf(v2, v3));
      m = fmaxf(m, __shfl_xor(m, 1));
      m = fmaxf(m, __shfl_xor(m, 2));
      float e0 = __expf(v0 - m), e1 = __expf(v1 - m);
      float e2 = __expf(v2 - m), e3 = __expf(v3 - m);
      float s = e0 + e1 + e2 + e3;
      s += __shfl_xor(s, 1);
      s += __shfl_xor(s, 2);
      float inv = 1.f / s;
      int row = row0 + rq * 4 + r;
      float4 o = make_float4(e0 * inv, e1 * inv, e2 * inv, e3 * inv);
      *(float4*)(awbuf + (size_t)row * 128 + c0) = o;
    }
  }
}

// ---------------------------------------------------------------------------
// K3: bilinear sampling + weighted sum. One wave per (b,q,h).
// 4 lane-groups x 16 lanes; group g handles point p=g; iteration l = level
// (wave-uniform, compile-time). Each lane loads 2 packed bf16 per corner.
// ---------------------------------------------------------------------------
__global__ __launch_bounds__(256) void sample_kernel(
    const __hip_bfloat16* __restrict__ vbh, const float* __restrict__ locbuf,
    const float* __restrict__ awbuf, float* __restrict__ sampled) {
  const int wid = (blockIdx.x * 256 + threadIdx.x) >> 6;
  const int lane = threadIdx.x & 63;
  const int h = wid & 7;
  const int row = wid >> 3;  // b*NQ + q
  const int b = row / NQ;
  const unsigned int* vb =
      (const unsigned int*)(vbh + ((size_t)(b * NH + h)) * NV * HD);
  const int grp = lane >> 4;  // point index
  const int d2 = lane & 15;   // dim pair: dims 2*d2, 2*d2+1

  const float* locp = locbuf + (size_t)row * 256 + h * 32;
  const float* awp = awbuf + (size_t)row * 128 + h * 16;

  float ax = 0.f, ay = 0.f;
#pragma unroll
  for (int l = 0; l < 4; ++l) {
    const int W_ = (l == 0) ? 100 : (l == 1) ? 50 : (l == 2) ? 25 : 13;
    const int H_ = W_;
    const int START = (l == 0) ? 0 : (l == 1) ? 10000 : (l == 2) ? 12500 : 13125;
    const int s = l * 4 + grp;
    const float2 xy = *(const float2*)(locp + s * 2);
    const float w = awp[s];

    const float fx = floorf(xy.x), fy = floorf(xy.y);
    const int x0 = (int)fx, y0 = (int)fy;
    const float wx1 = xy.x - fx, wy1 = xy.y - fy;
    const float wx0 = 1.f - wx1, wy0 = 1.f - wy1;

    const int x0c = min(max(x0, 0), W_ - 1), x1c = min(max(x0 + 1, 0), W_ - 1);
    const int y0c = min(max(y0, 0), H_ - 1), y1c = min(max(y0 + 1, 0), H_ - 1);
    const float mx0 = (x0 >= 0 && x0 < W_) ? wx0 : 0.f;
    const float mx1 = (x0 + 1 >= 0 && x0 + 1 < W_) ? wx1 : 0.f;
    const float my0 = (y0 >= 0 && y0 < H_) ? wy0 : 0.f;
    const float my1 = (y0 + 1 >= 0 && y0 + 1 < H_) ? wy1 : 0.f;

    const unsigned int* basep = vb + (size_t)START * 16 + d2;
    unsigned int u00 = basep[(y0c * W_ + x0c) * 16];
    unsigned int u01 = basep[(y0c * W_ + x1c) * 16];
    unsigned int u10 = basep[(y1c * W_ + x0c) * 16];
    unsigned int u11 = basep[(y1c * W_ + x1c) * 16];

    const float w00 = w * my0 * mx0, w01 = w * my0 * mx1;
    const float w10 = w * my1 * mx0, w11 = w * my1 * mx1;
    ax += w00 * bflo(u00) + w01 * bflo(u01) + w10 * bflo(u10) + w11 * bflo(u11);
    ay += w00 * bfhi(u00) + w01 * bfhi(u01) + w10 * bfhi(u10) + w11 * bfhi(u11);
  }
  ax += __shfl_xor(ax, 16);
  ax += __shfl_xor(ax, 32);
  ay += __shfl_xor(ay, 16);
  ay += __shfl_xor(ay, 32);
  if (grp == 0) {
    *(float2*)(sampled + (size_t)row * EMB + h * HD + 2 * d2) =
        make_float2(ax, ay);
  }
}

// ---------------------------------------------------------------------------
// K4: out = sampled @ W_out + b_out + query (residual fused), 4x4 blocking.
// ---------------------------------------------------------------------------
__global__ __launch_bounds__(256) void oproj_kernel(
    const float* __restrict__ sampled, const float* __restrict__ W_out,
    const float* __restrict__ b_out, const float* __restrict__ query,
    float* __restrict__ out) {
  constexpr int ROWS = 16;
  __shared__ float ldsA[ROWS * EMB];
  const int row0 = blockIdx.x * ROWS;
  const int tid = threadIdx.x;
  const int rq = tid >> 6;
  const int c4 = tid & 63;

  for (int idx = tid; idx < ROWS * 64; idx += 256) {
    int r = idx >> 6, k4 = idx & 63;
    *(float4*)(ldsA + r * EMB + k4 * 4) =
        *(const float4*)(sampled + (size_t)(row0 + r) * EMB + k4 * 4);
  }
  __syncthreads();

  float4 acc[4];
#pragma unroll
  for (int r = 0; r < 4; r++) acc[r] = make_float4(0.f, 0.f, 0.f, 0.f);

  const float* ldsBase = ldsA + rq * 4 * EMB;
  const float* Wb = W_out + 4 * c4;
  for (int k4 = 0; k4 < 64; ++k4) {
    float4 w0 = *(const float4*)(Wb + (4 * k4 + 0) * EMB);
    float4 w1 = *(const float4*)(Wb + (4 * k4 + 1) * EMB);
    float4 w2 = *(const float4*)(Wb + (4 * k4 + 2) * EMB);
    float4 w3 = *(const float4*)(Wb + (4 * k4 + 3) * EMB);
#pragma unroll
    for (int r = 0; r < 4; ++r) {
      float4 a = *(const float4*)(ldsBase + r * EMB + k4 * 4);
      acc[r].x += a.x * w0.x + a.y * w1.x + a.z * w2.x + a.w * w3.x;
      acc[r].y += a.x * w0.y + a.y * w1.y + a.z * w2.y + a.w * w3.y;
      acc[r].z += a.x * w0.z + a.y * w1.z + a.z * w2.z + a.w * w3.z;
      acc[r].w += a.x * w0.w + a.y * w1.w + a.z * w2.w + a.w * w3.w;
    }
  }

  const float4 bias = *(const float4*)(b_out + 4 * c4);
#pragma unroll
  for (int r = 0; r < 4; ++r) {
    size_t row = row0 + rq * 4 + r;
    float4 q = *(const float4*)(query + row * EMB + 4 * c4);
    float4 o;
    o.x = acc[r].x + bias.x + q.x;
    o.y = acc[r].y + bias.y + q.y;
    o.z = acc[r].z + bias.z + q.z;
    o.w = acc[r].w + bias.w + q.w;
    *(float4*)(out + row * EMB + 4 * c4) = o;
  }
}

// ---------------------------------------------------------------------------
extern "C" void kernel_launch(void* const* d_in, const int* in_sizes, int n_in,
                              void* d_out, int out_size, void* d_ws,
                              size_t ws_size, hipStream_t stream) {
  const float* query  = (const float*)d_in[0];
  const float* value  = (const float*)d_in[1];
  const float* refpts = (const float*)d_in[2];
  const float* W_off  = (const float*)d_in[3];
  const float* b_off  = (const float*)d_in[4];
  const float* W_attn = (const float*)d_in[5];
  const float* b_attn = (const float*)d_in[6];
  const float* W_val  = (const float*)d_in[7];
  const float* b_val  = (const float*)d_in[8];
  const float* W_out  = (const float*)d_in[9];
  const float* b_out  = (const float*)d_in[10];
  float* out = (float*)d_out;

  char* ws = (char*)d_ws;
  __hip_bfloat16* vbh = (__hip_bfloat16*)ws;                       // 27,226,112 B
  float* locbuf = (float*)(ws + 27226112);                         // 24,576,000 B
  float* awbuf  = (float*)(ws + 27226112 + 24576000);              // 12,288,000 B
  float* sampled = (float*)(ws + 27226112 + 24576000 + 12288000);  // 24,576,000 B

  vproj_kernel<<<(BS * NV + 15) / 16, 256, 0, stream>>>(value, W_val, b_val, vbh);
  qproj_kernel<<<BS * NQ / 16, 384, 0, stream>>>(query, refpts, W_off, b_off,
                                                 W_attn, b_attn, locbuf, awbuf);
  sample_kernel<<<BS * NQ * NH / 4, 256, 0, stream>>>(vbh, locbuf, awbuf, sampled);
  oproj_kernel<<<BS * NQ / 16, 256, 0, stream>>>(sampled, W_out, b_out, query, out);
}

// Round 3
// 282.697 us; speedup vs baseline: 2.8554x; 1.9183x over previous
//
#include <hip/hip_runtime.h>
#include <hip/hip_bf16.h>

#define BS 4
#define NQ 6000
#define NV 13294
#define NH 8
#define HD 32
#define EMB 256
#define MV (BS * NV)  // 53176
#define MQ (BS * NQ)  // 24000

typedef __attribute__((ext_vector_type(8))) short short8;
typedef __attribute__((ext_vector_type(4))) float floatx4;

__device__ __constant__ float LVL_DIM[4] = {100.f, 50.f, 25.f, 13.f};

__device__ inline unsigned short bf16bits(float f) {
  __hip_bfloat16 h = __float2bfloat16(f);
  return *reinterpret_cast<unsigned short*>(&h);
}
__device__ inline float bflo(unsigned int u) { return __uint_as_float(u << 16); }
__device__ inline float bfhi(unsigned int u) { return __uint_as_float(u & 0xffff0000u); }

#define LDS_STRIDE 40  // 32 + 8 pad: bank aliasing <=2-way for ds_read_b128

// ---------------------------------------------------------------------------
// Weight transpose + bf16 convert: Wt[n][k] = bf16(W[k][n]).
// blocks 0..255 -> Wt_val; 256..639 -> Wt_qcat (W_off cols then W_attn cols);
// 640..895 -> Wt_out. One output row per block, k = threadIdx.x.
// ---------------------------------------------------------------------------
__global__ __launch_bounds__(256) void wtrans_kernel(
    const float* __restrict__ W_val, const float* __restrict__ W_off,
    const float* __restrict__ W_attn, const float* __restrict__ W_out,
    unsigned short* __restrict__ Wt_val, unsigned short* __restrict__ Wt_qcat,
    unsigned short* __restrict__ Wt_out) {
  const int b = blockIdx.x, k = threadIdx.x;
  if (b < 256) {
    Wt_val[b * EMB + k] = bf16bits(W_val[k * 256 + b]);
  } else if (b < 640) {
    const int n = b - 256;
    float v = (n < 256) ? W_off[k * 256 + n] : W_attn[k * 128 + (n - 256)];
    Wt_qcat[n * EMB + k] = bf16bits(v);
  } else {
    const int n = b - 640;
    Wt_out[n * EMB + k] = bf16bits(W_out[k * 256 + n]);
  }
}

// ---------------------------------------------------------------------------
// Shared MFMA-GEMM helpers. 128x128 tile, 4 waves, 64x64 per wave,
// 4x4 of mfma_f32_16x16x32_bf16, BK=32.
// ---------------------------------------------------------------------------
__device__ inline void stageA_f32(const float* __restrict__ A, int M, int m0,
                                  int k0, unsigned short* lds, int tid) {
  const int r = tid >> 1, half = tid & 1;
  const int row = m0 + r;
  unsigned short* dst = lds + r * LDS_STRIDE + half * 16;
  if (row < M) {
    const float* src = A + (size_t)row * EMB + k0 + half * 16;
#pragma unroll
    for (int j = 0; j < 4; ++j) {
      float4 v = *(const float4*)(src + 4 * j);
      ushort4 u;
      u.x = bf16bits(v.x);
      u.y = bf16bits(v.y);
      u.z = bf16bits(v.z);
      u.w = bf16bits(v.w);
      *(ushort4*)(dst + 4 * j) = u;
    }
  } else {
    ushort4 z = make_ushort4(0, 0, 0, 0);
#pragma unroll
    for (int j = 0; j < 4; ++j) *(ushort4*)(dst + 4 * j) = z;
  }
}

__device__ inline void stage_bf16(const unsigned short* __restrict__ B, int M,
                                  int n0, int k0, unsigned short* lds, int tid) {
  const int r = tid >> 1, half = tid & 1;
  const int row = n0 + r;
  unsigned short* dst = lds + r * LDS_STRIDE + half * 16;
  if (row < M) {
    const unsigned short* src = B + (size_t)row * EMB + k0 + half * 16;
    uint4 v0 = *(const uint4*)(src);
    uint4 v1 = *(const uint4*)(src + 8);
    *(uint4*)(dst) = v0;
    *(uint4*)(dst + 8) = v1;
  } else {
    uint4 z = make_uint4(0, 0, 0, 0);
    *(uint4*)(dst) = z;
    *(uint4*)(dst + 8) = z;
  }
}

__device__ inline void mfma_step(const unsigned short* ldsA,
                                 const unsigned short* ldsB, int wm, int wn,
                                 int lane, floatx4 acc[4][4]) {
  const unsigned short* ap =
      ldsA + (wm * 64 + (lane & 15)) * LDS_STRIDE + (lane >> 4) * 8;
  const unsigned short* bp =
      ldsB + (wn * 64 + (lane & 15)) * LDS_STRIDE + (lane >> 4) * 8;
  short8 af[4], bfr[4];
#pragma unroll
  for (int t = 0; t < 4; ++t) {
    af[t] = *(const short8*)(ap + t * 16 * LDS_STRIDE);
    bfr[t] = *(const short8*)(bp + t * 16 * LDS_STRIDE);
  }
#pragma unroll
  for (int mt = 0; mt < 4; ++mt)
#pragma unroll
    for (int nt = 0; nt < 4; ++nt)
      acc[mt][nt] = __builtin_amdgcn_mfma_f32_16x16x32_bf16(af[mt], bfr[nt],
                                                            acc[mt][nt], 0, 0, 0);
}

// ---------------------------------------------------------------------------
// K1: v = value @ W_val + b_val -> bf16 [b, h, nv, 32]
// ---------------------------------------------------------------------------
__global__ __launch_bounds__(256) void vproj_kernel(
    const float* __restrict__ value, const unsigned short* __restrict__ Wt,
    const float* __restrict__ b_val, unsigned short* __restrict__ vbh) {
  __shared__ unsigned short ldsA[128 * LDS_STRIDE];
  __shared__ unsigned short ldsB[128 * LDS_STRIDE];
  const int tid = threadIdx.x, lane = tid & 63, w = tid >> 6;
  const int wm = w >> 1, wn = w & 1;
  const int m0 = (blockIdx.x >> 1) * 128;
  const int n0 = (blockIdx.x & 1) * 128;
  floatx4 acc[4][4];
  const floatx4 zero = {0.f, 0.f, 0.f, 0.f};
#pragma unroll
  for (int i = 0; i < 4; i++)
#pragma unroll
    for (int j = 0; j < 4; j++) acc[i][j] = zero;

  for (int k0 = 0; k0 < EMB; k0 += 32) {
    stageA_f32(value, MV, m0, k0, ldsA, tid);
    stage_bf16(Wt, 256, n0, k0, ldsB, tid);
    __syncthreads();
    mfma_step(ldsA, ldsB, wm, wn, lane, acc);
    __syncthreads();
  }

  const int quad = lane >> 4, cl = lane & 15;
#pragma unroll
  for (int mt = 0; mt < 4; ++mt) {
#pragma unroll
    for (int r = 0; r < 4; ++r) {
      const int row = m0 + wm * 64 + mt * 16 + quad * 4 + r;
      if (row < MV) {
        const int b = row / NV, n = row - b * NV;
#pragma unroll
        for (int nt = 0; nt < 4; ++nt) {
          const int c = n0 + wn * 64 + nt * 16 + cl;
          const int h = c >> 5, d = c & 31;
          vbh[(((size_t)(b * NH + h)) * NV + n) * HD + d] =
              bf16bits(acc[mt][nt][r] + b_val[c]);
        }
      }
    }
  }
}

// ---------------------------------------------------------------------------
// K2: [offsets | attn] = query @ [W_off | W_attn]; epilogue: pixel coords
// (n0 < 256) or 16-wide shuffle softmax (n0 == 256).
// ---------------------------------------------------------------------------
__global__ __launch_bounds__(256) void qproj_kernel(
    const float* __restrict__ query, const unsigned short* __restrict__ Wt,
    const float* __restrict__ refpts, const float* __restrict__ b_off,
    const float* __restrict__ b_attn, float* __restrict__ locbuf,
    float* __restrict__ awbuf) {
  __shared__ unsigned short ldsA[128 * LDS_STRIDE];
  __shared__ unsigned short ldsB[128 * LDS_STRIDE];
  const int tid = threadIdx.x, lane = tid & 63, w = tid >> 6;
  const int wm = w >> 1, wn = w & 1;
  const int m0 = (blockIdx.x / 3) * 128;
  const int n0 = (blockIdx.x % 3) * 128;
  floatx4 acc[4][4];
  const floatx4 zero = {0.f, 0.f, 0.f, 0.f};
#pragma unroll
  for (int i = 0; i < 4; i++)
#pragma unroll
    for (int j = 0; j < 4; j++) acc[i][j] = zero;

  for (int k0 = 0; k0 < EMB; k0 += 32) {
    stageA_f32(query, MQ, m0, k0, ldsA, tid);
    stage_bf16(Wt, 384, n0, k0, ldsB, tid);
    __syncthreads();
    mfma_step(ldsA, ldsB, wm, wn, lane, acc);
    __syncthreads();
  }

  const int quad = lane >> 4, cl = lane & 15;
  if (n0 < 256) {  // offset region: c in [0,256)
#pragma unroll
    for (int mt = 0; mt < 4; ++mt) {
#pragma unroll
      for (int r = 0; r < 4; ++r) {
        const int row = m0 + wm * 64 + mt * 16 + quad * 4 + r;
        if (row < MQ) {
#pragma unroll
          for (int nt = 0; nt < 4; ++nt) {
            const int c = n0 + wn * 64 + nt * 16 + cl;
            const int xy = c & 1, l = (c >> 3) & 3;
            const float dim = LVL_DIM[l];
            const float ref = refpts[(size_t)row * 8 + l * 2 + xy];
            locbuf[(size_t)row * 256 + c] =
                ref * dim + acc[mt][nt][r] + b_off[c] - 0.5f;
          }
        }
      }
    }
  } else {  // attn region: ca in [0,128), softmax over 16 consecutive cols
#pragma unroll
    for (int mt = 0; mt < 4; ++mt) {
#pragma unroll
      for (int r = 0; r < 4; ++r) {
        const int row = m0 + wm * 64 + mt * 16 + quad * 4 + r;
        if (row < MQ) {
#pragma unroll
          for (int nt = 0; nt < 4; ++nt) {
            const int ca = wn * 64 + nt * 16 + cl;
            float v = acc[mt][nt][r] + b_attn[ca];
            float m = v;
            m = fmaxf(m, __shfl_xor(m, 1));
            m = fmaxf(m, __shfl_xor(m, 2));
            m = fmaxf(m, __shfl_xor(m, 4));
            m = fmaxf(m, __shfl_xor(m, 8));
            float e = __expf(v - m);
            float s = e;
            s += __shfl_xor(s, 1);
            s += __shfl_xor(s, 2);
            s += __shfl_xor(s, 4);
            s += __shfl_xor(s, 8);
            awbuf[(size_t)row * 128 + ca] = e / s;
          }
        }
      }
    }
  }
}

// ---------------------------------------------------------------------------
// K3: bilinear sampling + weighted sum -> bf16 sampled
// ---------------------------------------------------------------------------
__global__ __launch_bounds__(256) void sample_kernel(
    const unsigned short* __restrict__ vbh, const float* __restrict__ locbuf,
    const float* __restrict__ awbuf, unsigned short* __restrict__ sampledb) {
  const int wid = (blockIdx.x * 256 + threadIdx.x) >> 6;
  const int lane = threadIdx.x & 63;
  const int h = wid & 7;
  const int row = wid >> 3;  // b*NQ + q
  const int b = row / NQ;
  const unsigned int* vb =
      (const unsigned int*)(vbh) + ((size_t)(b * NH + h)) * NV * 16;
  const int grp = lane >> 4;  // point index
  const int d2 = lane & 15;   // dim pair

  const float* locp = locbuf + (size_t)row * 256 + h * 32;
  const float* awp = awbuf + (size_t)row * 128 + h * 16;

  float ax = 0.f, ay = 0.f;
#pragma unroll
  for (int l = 0; l < 4; ++l) {
    const int W_ = (l == 0) ? 100 : (l == 1) ? 50 : (l == 2) ? 25 : 13;
    const int H_ = W_;
    const int START = (l == 0) ? 0 : (l == 1) ? 10000 : (l == 2) ? 12500 : 13125;
    const int s = l * 4 + grp;
    const float2 xy = *(const float2*)(locp + s * 2);
    const float w = awp[s];

    const float fx = floorf(xy.x), fy = floorf(xy.y);
    const int x0 = (int)fx, y0 = (int)fy;
    const float wx1 = xy.x - fx, wy1 = xy.y - fy;
    const float wx0 = 1.f - wx1, wy0 = 1.f - wy1;

    const int x0c = min(max(x0, 0), W_ - 1), x1c = min(max(x0 + 1, 0), W_ - 1);
    const int y0c = min(max(y0, 0), H_ - 1), y1c = min(max(y0 + 1, 0), H_ - 1);
    const float mx0 = (x0 >= 0 && x0 < W_) ? wx0 : 0.f;
    const float mx1 = (x0 + 1 >= 0 && x0 + 1 < W_) ? wx1 : 0.f;
    const float my0 = (y0 >= 0 && y0 < H_) ? wy0 : 0.f;
    const float my1 = (y0 + 1 >= 0 && y0 + 1 < H_) ? wy1 : 0.f;

    const unsigned int* basep = vb + (size_t)START * 16 + d2;
    unsigned int u00 = basep[(y0c * W_ + x0c) * 16];
    unsigned int u01 = basep[(y0c * W_ + x1c) * 16];
    unsigned int u10 = basep[(y1c * W_ + x0c) * 16];
    unsigned int u11 = basep[(y1c * W_ + x1c) * 16];

    const float w00 = w * my0 * mx0, w01 = w * my0 * mx1;
    const float w10 = w * my1 * mx0, w11 = w * my1 * mx1;
    ax += w00 * bflo(u00) + w01 * bflo(u01) + w10 * bflo(u10) + w11 * bflo(u11);
    ay += w00 * bfhi(u00) + w01 * bfhi(u01) + w10 * bfhi(u10) + w11 * bfhi(u11);
  }
  ax += __shfl_xor(ax, 16);
  ax += __shfl_xor(ax, 32);
  ay += __shfl_xor(ay, 16);
  ay += __shfl_xor(ay, 32);
  if (grp == 0) {
    ushort2 o;
    o.x = bf16bits(ax);
    o.y = bf16bits(ay);
    *(ushort2*)(sampledb + (size_t)row * EMB + h * HD + 2 * d2) = o;
  }
}

// ---------------------------------------------------------------------------
// K4: out = sampled @ W_out + b_out + query (residual fused)
// ---------------------------------------------------------------------------
__global__ __launch_bounds__(256) void oproj_kernel(
    const unsigned short* __restrict__ sampledb,
    const unsigned short* __restrict__ Wt, const float* __restrict__ b_out,
    const float* __restrict__ query, float* __restrict__ out) {
  __shared__ unsigned short ldsA[128 * LDS_STRIDE];
  __shared__ unsigned short ldsB[128 * LDS_STRIDE];
  const int tid = threadIdx.x, lane = tid & 63, w = tid >> 6;
  const int wm = w >> 1, wn = w & 1;
  const int m0 = (blockIdx.x >> 1) * 128;
  const int n0 = (blockIdx.x & 1) * 128;
  floatx4 acc[4][4];
  const floatx4 zero = {0.f, 0.f, 0.f, 0.f};
#pragma unroll
  for (int i = 0; i < 4; i++)
#pragma unroll
    for (int j = 0; j < 4; j++) acc[i][j] = zero;

  for (int k0 = 0; k0 < EMB; k0 += 32) {
    stage_bf16(sampledb, MQ, m0, k0, ldsA, tid);
    stage_bf16(Wt, 256, n0, k0, ldsB, tid);
    __syncthreads();
    mfma_step(ldsA, ldsB, wm, wn, lane, acc);
    __syncthreads();
  }

  const int quad = lane >> 4, cl = lane & 15;
#pragma unroll
  for (int mt = 0; mt < 4; ++mt) {
#pragma unroll
    for (int r = 0; r < 4; ++r) {
      const int row = m0 + wm * 64 + mt * 16 + quad * 4 + r;
      if (row < MQ) {
#pragma unroll
        for (int nt = 0; nt < 4; ++nt) {
          const int c = n0 + wn * 64 + nt * 16 + cl;
          out[(size_t)row * EMB + c] =
              acc[mt][nt][r] + b_out[c] + query[(size_t)row * EMB + c];
        }
      }
    }
  }
}

// ---------------------------------------------------------------------------
extern "C" void kernel_launch(void* const* d_in, const int* in_sizes, int n_in,
                              void* d_out, int out_size, void* d_ws,
                              size_t ws_size, hipStream_t stream) {
  const float* query  = (const float*)d_in[0];
  const float* value  = (const float*)d_in[1];
  const float* refpts = (const float*)d_in[2];
  const float* W_off  = (const float*)d_in[3];
  const float* b_off  = (const float*)d_in[4];
  const float* W_attn = (const float*)d_in[5];
  const float* b_attn = (const float*)d_in[6];
  const float* W_val  = (const float*)d_in[7];
  const float* b_val  = (const float*)d_in[8];
  const float* W_out  = (const float*)d_in[9];
  const float* b_out  = (const float*)d_in[10];
  float* out = (float*)d_out;

  char* ws = (char*)d_ws;
  unsigned short* vbh = (unsigned short*)ws;                   // 27,226,112 B
  float* locbuf = (float*)(ws + 27226112);                     // 24,576,000 B
  float* awbuf = (float*)(ws + 51802112);                      // 12,288,000 B
  unsigned short* sampledb = (unsigned short*)(ws + 64090112); // 12,288,000 B
  unsigned short* Wt_val = (unsigned short*)(ws + 76378112);   //    131,072 B
  unsigned short* Wt_qcat = (unsigned short*)(ws + 76509184);  //    196,608 B
  unsigned short* Wt_out = (unsigned short*)(ws + 76705792);   //    131,072 B

  wtrans_kernel<<<896, 256, 0, stream>>>(W_val, W_off, W_attn, W_out, Wt_val,
                                         Wt_qcat, Wt_out);
  vproj_kernel<<<416 * 2, 256, 0, stream>>>(value, Wt_val, b_val, vbh);
  qproj_kernel<<<188 * 3, 256, 0, stream>>>(query, Wt_qcat, refpts, b_off,
                                            b_attn, locbuf, awbuf);
  sample_kernel<<<BS * NQ * NH / 4, 256, 0, stream>>>(vbh, locbuf, awbuf,
                                                      sampledb);
  oproj_kernel<<<188 * 2, 256, 0, stream>>>(sampledb, Wt_out, b_out, query, out);
}

// Round 4
// 262.546 us; speedup vs baseline: 3.0746x; 1.0768x over previous
//
#include <hip/hip_runtime.h>
#include <hip/hip_bf16.h>

#define BS 4
#define NQ 6000
#define NV 13294
#define NH 8
#define HD 32
#define EMB 256
#define MV (BS * NV)  // 53176
#define MQ (BS * NQ)  // 24000

typedef __attribute__((ext_vector_type(8))) short short8;
typedef __attribute__((ext_vector_type(4))) float floatx4;

__device__ __constant__ float LVL_DIM[4] = {100.f, 50.f, 25.f, 13.f};

__device__ inline unsigned short bf16bits(float f) {
  __hip_bfloat16 h = __float2bfloat16(f);
  return *reinterpret_cast<unsigned short*>(&h);
}
__device__ inline float bflo(unsigned int u) { return __uint_as_float(u << 16); }
__device__ inline float bfhi(unsigned int u) { return __uint_as_float(u & 0xffff0000u); }

#define LDS_STRIDE 40  // 32 + 8 pad: bank aliasing <=2-way for ds_read_b128

// ---------------------------------------------------------------------------
// Weight transpose + bf16 convert: Wt[n][k] = bf16(W[k][n]).
// ---------------------------------------------------------------------------
__global__ __launch_bounds__(256) void wtrans_kernel(
    const float* __restrict__ W_val, const float* __restrict__ W_off,
    const float* __restrict__ W_attn, const float* __restrict__ W_out,
    unsigned short* __restrict__ Wt_val, unsigned short* __restrict__ Wt_qcat,
    unsigned short* __restrict__ Wt_out) {
  const int b = blockIdx.x, k = threadIdx.x;
  if (b < 256) {
    Wt_val[b * EMB + k] = bf16bits(W_val[k * 256 + b]);
  } else if (b < 640) {
    const int n = b - 256;
    float v = (n < 256) ? W_off[k * 256 + n] : W_attn[k * 128 + (n - 256)];
    Wt_qcat[n * EMB + k] = bf16bits(v);
  } else {
    const int n = b - 640;
    Wt_out[n * EMB + k] = bf16bits(W_out[k * 256 + n]);
  }
}

// ---------------------------------------------------------------------------
// Shared MFMA-GEMM helpers. 128x128 tile, 4 waves, 64x64 per wave,
// 4x4 of mfma_f32_16x16x32_bf16, BK=32.
// ---------------------------------------------------------------------------
__device__ inline void stageA_f32(const float* __restrict__ A, int M, int m0,
                                  int k0, unsigned short* lds, int tid) {
  const int r = tid >> 1, half = tid & 1;
  const int row = m0 + r;
  unsigned short* dst = lds + r * LDS_STRIDE + half * 16;
  if (row < M) {
    const float* src = A + (size_t)row * EMB + k0 + half * 16;
#pragma unroll
    for (int j = 0; j < 4; ++j) {
      float4 v = *(const float4*)(src + 4 * j);
      ushort4 u;
      u.x = bf16bits(v.x);
      u.y = bf16bits(v.y);
      u.z = bf16bits(v.z);
      u.w = bf16bits(v.w);
      *(ushort4*)(dst + 4 * j) = u;
    }
  } else {
    ushort4 z = make_ushort4(0, 0, 0, 0);
#pragma unroll
    for (int j = 0; j < 4; ++j) *(ushort4*)(dst + 4 * j) = z;
  }
}

__device__ inline void stage_bf16(const unsigned short* __restrict__ B, int M,
                                  int n0, int k0, unsigned short* lds, int tid) {
  const int r = tid >> 1, half = tid & 1;
  const int row = n0 + r;
  unsigned short* dst = lds + r * LDS_STRIDE + half * 16;
  if (row < M) {
    const unsigned short* src = B + (size_t)row * EMB + k0 + half * 16;
    uint4 v0 = *(const uint4*)(src);
    uint4 v1 = *(const uint4*)(src + 8);
    *(uint4*)(dst) = v0;
    *(uint4*)(dst + 8) = v1;
  } else {
    uint4 z = make_uint4(0, 0, 0, 0);
    *(uint4*)(dst) = z;
    *(uint4*)(dst + 8) = z;
  }
}

__device__ inline void mfma_step(const unsigned short* ldsA,
                                 const unsigned short* ldsB, int wm, int wn,
                                 int lane, floatx4 acc[4][4]) {
  const unsigned short* ap =
      ldsA + (wm * 64 + (lane & 15)) * LDS_STRIDE + (lane >> 4) * 8;
  const unsigned short* bp =
      ldsB + (wn * 64 + (lane & 15)) * LDS_STRIDE + (lane >> 4) * 8;
  short8 af[4], bfr[4];
#pragma unroll
  for (int t = 0; t < 4; ++t) {
    af[t] = *(const short8*)(ap + t * 16 * LDS_STRIDE);
    bfr[t] = *(const short8*)(bp + t * 16 * LDS_STRIDE);
  }
#pragma unroll
  for (int mt = 0; mt < 4; ++mt)
#pragma unroll
    for (int nt = 0; nt < 4; ++nt)
      acc[mt][nt] = __builtin_amdgcn_mfma_f32_16x16x32_bf16(af[mt], bfr[nt],
                                                            acc[mt][nt], 0, 0, 0);
}

// ---------------------------------------------------------------------------
// K1: v = value @ W_val + b_val -> bf16 [b, h, nv, 32]
// Sibling swizzle: chunks of 16 blocks = 8 m-tiles x 2 n-tiles; siblings
// (same m, different n) are 8 apart -> same XCD round-robin slot.
// ---------------------------------------------------------------------------
__global__ __launch_bounds__(256) void vproj_kernel(
    const float* __restrict__ value, const unsigned short* __restrict__ Wt,
    const float* __restrict__ b_val, unsigned short* __restrict__ vbh) {
  __shared__ unsigned short ldsA[128 * LDS_STRIDE];
  __shared__ unsigned short ldsB[128 * LDS_STRIDE];
  const int tid = threadIdx.x, lane = tid & 63, w = tid >> 6;
  const int wm = w >> 1, wn = w & 1;
  const int chunk = blockIdx.x >> 4, i = blockIdx.x & 15;
  const int m0 = (chunk * 8 + (i & 7)) * 128;
  const int n0 = (i >> 3) * 128;
  floatx4 acc[4][4];
  const floatx4 zero = {0.f, 0.f, 0.f, 0.f};
#pragma unroll
  for (int i2 = 0; i2 < 4; i2++)
#pragma unroll
    for (int j = 0; j < 4; j++) acc[i2][j] = zero;

  for (int k0 = 0; k0 < EMB; k0 += 32) {
    stageA_f32(value, MV, m0, k0, ldsA, tid);
    stage_bf16(Wt, 256, n0, k0, ldsB, tid);
    __syncthreads();
    mfma_step(ldsA, ldsB, wm, wn, lane, acc);
    __syncthreads();
  }

  const int quad = lane >> 4, cl = lane & 15;
#pragma unroll
  for (int mt = 0; mt < 4; ++mt) {
#pragma unroll
    for (int r = 0; r < 4; ++r) {
      const int row = m0 + wm * 64 + mt * 16 + quad * 4 + r;
      if (row < MV) {
        const int b = row / NV, n = row - b * NV;
#pragma unroll
        for (int nt = 0; nt < 4; ++nt) {
          const int c = n0 + wn * 64 + nt * 16 + cl;
          const int h = c >> 5, d = c & 31;
          vbh[(((size_t)(b * NH + h)) * NV + n) * HD + d] =
              bf16bits(acc[mt][nt][r] + b_val[c]);
        }
      }
    }
  }
}

// ---------------------------------------------------------------------------
// K2: [offsets | attn] = query @ [W_off | W_attn]; chunks of 24 blocks =
// 8 m-tiles x 3 n-tiles (m padded to 192, guard).
// ---------------------------------------------------------------------------
__global__ __launch_bounds__(256) void qproj_kernel(
    const float* __restrict__ query, const unsigned short* __restrict__ Wt,
    const float* __restrict__ refpts, const float* __restrict__ b_off,
    const float* __restrict__ b_attn, float* __restrict__ locbuf,
    float* __restrict__ awbuf) {
  __shared__ unsigned short ldsA[128 * LDS_STRIDE];
  __shared__ unsigned short ldsB[128 * LDS_STRIDE];
  const int tid = threadIdx.x, lane = tid & 63, w = tid >> 6;
  const int wm = w >> 1, wn = w & 1;
  const int chunk = blockIdx.x / 24, i = blockIdx.x % 24;
  const int m_idx = chunk * 8 + (i & 7);
  if (m_idx >= 188) return;
  const int m0 = m_idx * 128;
  const int n0 = (i >> 3) * 128;
  floatx4 acc[4][4];
  const floatx4 zero = {0.f, 0.f, 0.f, 0.f};
#pragma unroll
  for (int i2 = 0; i2 < 4; i2++)
#pragma unroll
    for (int j = 0; j < 4; j++) acc[i2][j] = zero;

  for (int k0 = 0; k0 < EMB; k0 += 32) {
    stageA_f32(query, MQ, m0, k0, ldsA, tid);
    stage_bf16(Wt, 384, n0, k0, ldsB, tid);
    __syncthreads();
    mfma_step(ldsA, ldsB, wm, wn, lane, acc);
    __syncthreads();
  }

  const int quad = lane >> 4, cl = lane & 15;
  if (n0 < 256) {  // offset region
#pragma unroll
    for (int mt = 0; mt < 4; ++mt) {
#pragma unroll
      for (int r = 0; r < 4; ++r) {
        const int row = m0 + wm * 64 + mt * 16 + quad * 4 + r;
        if (row < MQ) {
#pragma unroll
          for (int nt = 0; nt < 4; ++nt) {
            const int c = n0 + wn * 64 + nt * 16 + cl;
            const int xy = c & 1, l = (c >> 3) & 3;
            const float dim = LVL_DIM[l];
            const float ref = refpts[(size_t)row * 8 + l * 2 + xy];
            locbuf[(size_t)row * 256 + c] =
                ref * dim + acc[mt][nt][r] + b_off[c] - 0.5f;
          }
        }
      }
    }
  } else {  // attn region: softmax over 16 consecutive cols
#pragma unroll
    for (int mt = 0; mt < 4; ++mt) {
#pragma unroll
      for (int r = 0; r < 4; ++r) {
        const int row = m0 + wm * 64 + mt * 16 + quad * 4 + r;
        if (row < MQ) {
#pragma unroll
          for (int nt = 0; nt < 4; ++nt) {
            const int ca = wn * 64 + nt * 16 + cl;
            float v = acc[mt][nt][r] + b_attn[ca];
            float m = v;
            m = fmaxf(m, __shfl_xor(m, 1));
            m = fmaxf(m, __shfl_xor(m, 2));
            m = fmaxf(m, __shfl_xor(m, 4));
            m = fmaxf(m, __shfl_xor(m, 8));
            float e = __expf(v - m);
            float s = e;
            s += __shfl_xor(s, 1);
            s += __shfl_xor(s, 2);
            s += __shfl_xor(s, 4);
            s += __shfl_xor(s, 8);
            awbuf[(size_t)row * 128 + ca] = e / s;
          }
        }
      }
    }
  }
}

// ---------------------------------------------------------------------------
// K3: bilinear sampling. 16 sample-groups x 4 lanes; lane owns 8 dims
// (dwordx4 per corner). XCD-pinned: blockIdx&7 selects 4 (b,h) slices
// (3.4 MB working set < 4 MB per-XCD L2).
// ---------------------------------------------------------------------------
__global__ __launch_bounds__(256) void sample_kernel(
    const unsigned short* __restrict__ vbh, const float* __restrict__ locbuf,
    const float* __restrict__ awbuf, unsigned short* __restrict__ sampledb) {
  const int blk = blockIdx.x;
  const int t = blk >> 3;
  const int quarter = t / 1500;
  const int j = t - quarter * 1500;
  const int slice = (blk & 7) * 4 + quarter;  // b*8+h
  const int h = slice & 7;
  const int w = threadIdx.x >> 6;
  const int lane = threadIdx.x & 63;
  const int row = (slice >> 3) * NQ + j * 4 + w;  // b*NQ + q
  const int g = lane >> 2;  // sample 0..15: l = g>>2, p = g&3
  const int d8 = lane & 3;  // dim octet
  const int l = g >> 2;

  const int W_ = (l < 2) ? ((l == 0) ? 100 : 50) : ((l == 2) ? 25 : 13);
  const int START = (l < 2) ? ((l == 0) ? 0 : 10000) : ((l == 2) ? 12500 : 13125);

  const float2 xy = *(const float2*)(locbuf + (size_t)row * 256 + h * 32 + g * 2);
  const float wgt = awbuf[(size_t)row * 128 + h * 16 + g];

  const float fx = floorf(xy.x), fy = floorf(xy.y);
  const int x0 = (int)fx, y0 = (int)fy;
  const float wx1 = xy.x - fx, wy1 = xy.y - fy;
  const float wx0 = 1.f - wx1, wy0 = 1.f - wy1;
  const int x0c = min(max(x0, 0), W_ - 1), x1c = min(max(x0 + 1, 0), W_ - 1);
  const int y0c = min(max(y0, 0), W_ - 1), y1c = min(max(y0 + 1, 0), W_ - 1);
  const float mx0 = ((unsigned)x0 < (unsigned)W_) ? wx0 : 0.f;
  const float mx1 = ((unsigned)(x0 + 1) < (unsigned)W_) ? wx1 : 0.f;
  const float my0 = ((unsigned)y0 < (unsigned)W_) ? wy0 : 0.f;
  const float my1 = ((unsigned)(y0 + 1) < (unsigned)W_) ? wy1 : 0.f;
  const float wy0w = wgt * my0, wy1w = wgt * my1;
  const float w00 = wy0w * mx0, w01 = wy0w * mx1;
  const float w10 = wy1w * mx0, w11 = wy1w * mx1;

  const unsigned int* base =
      (const unsigned int*)vbh + ((size_t)slice * NV + START) * 16 + d8 * 4;
  const int rb0 = y0c * W_, rb1 = y1c * W_;
  const uint4 u00 = *(const uint4*)(base + (size_t)(rb0 + x0c) * 16);
  const uint4 u01 = *(const uint4*)(base + (size_t)(rb0 + x1c) * 16);
  const uint4 u10 = *(const uint4*)(base + (size_t)(rb1 + x0c) * 16);
  const uint4 u11 = *(const uint4*)(base + (size_t)(rb1 + x1c) * 16);

  float a[8];
  const unsigned int* p00 = &u00.x;
  const unsigned int* p01 = &u01.x;
  const unsigned int* p10 = &u10.x;
  const unsigned int* p11 = &u11.x;
#pragma unroll
  for (int k = 0; k < 4; ++k) {
    a[2 * k] = w00 * bflo(p00[k]) + w01 * bflo(p01[k]) + w10 * bflo(p10[k]) +
               w11 * bflo(p11[k]);
    a[2 * k + 1] = w00 * bfhi(p00[k]) + w01 * bfhi(p01[k]) +
                   w10 * bfhi(p10[k]) + w11 * bfhi(p11[k]);
  }

#pragma unroll
  for (int k = 0; k < 8; ++k) {
    a[k] += __shfl_xor(a[k], 4);
    a[k] += __shfl_xor(a[k], 8);
    a[k] += __shfl_xor(a[k], 16);
    a[k] += __shfl_xor(a[k], 32);
  }

  if (g == 0) {
    uint4 o;
    o.x = (unsigned)bf16bits(a[0]) | ((unsigned)bf16bits(a[1]) << 16);
    o.y = (unsigned)bf16bits(a[2]) | ((unsigned)bf16bits(a[3]) << 16);
    o.z = (unsigned)bf16bits(a[4]) | ((unsigned)bf16bits(a[5]) << 16);
    o.w = (unsigned)bf16bits(a[6]) | ((unsigned)bf16bits(a[7]) << 16);
    *(uint4*)(sampledb + (size_t)row * EMB + h * 32 + d8 * 8) = o;
  }
}

// ---------------------------------------------------------------------------
// K4: out = sampled @ W_out + b_out + query; sibling swizzle like vproj,
// m padded to 192 (guard at 188).
// ---------------------------------------------------------------------------
__global__ __launch_bounds__(256) void oproj_kernel(
    const unsigned short* __restrict__ sampledb,
    const unsigned short* __restrict__ Wt, const float* __restrict__ b_out,
    const float* __restrict__ query, float* __restrict__ out) {
  __shared__ unsigned short ldsA[128 * LDS_STRIDE];
  __shared__ unsigned short ldsB[128 * LDS_STRIDE];
  const int tid = threadIdx.x, lane = tid & 63, w = tid >> 6;
  const int wm = w >> 1, wn = w & 1;
  const int chunk = blockIdx.x >> 4, i = blockIdx.x & 15;
  const int m_idx = chunk * 8 + (i & 7);
  if (m_idx >= 188) return;
  const int m0 = m_idx * 128;
  const int n0 = (i >> 3) * 128;
  floatx4 acc[4][4];
  const floatx4 zero = {0.f, 0.f, 0.f, 0.f};
#pragma unroll
  for (int i2 = 0; i2 < 4; i2++)
#pragma unroll
    for (int j = 0; j < 4; j++) acc[i2][j] = zero;

  for (int k0 = 0; k0 < EMB; k0 += 32) {
    stage_bf16(sampledb, MQ, m0, k0, ldsA, tid);
    stage_bf16(Wt, 256, n0, k0, ldsB, tid);
    __syncthreads();
    mfma_step(ldsA, ldsB, wm, wn, lane, acc);
    __syncthreads();
  }

  const int quad = lane >> 4, cl = lane & 15;
#pragma unroll
  for (int mt = 0; mt < 4; ++mt) {
#pragma unroll
    for (int r = 0; r < 4; ++r) {
      const int row = m0 + wm * 64 + mt * 16 + quad * 4 + r;
      if (row < MQ) {
#pragma unroll
        for (int nt = 0; nt < 4; ++nt) {
          const int c = n0 + wn * 64 + nt * 16 + cl;
          out[(size_t)row * EMB + c] =
              acc[mt][nt][r] + b_out[c] + query[(size_t)row * EMB + c];
        }
      }
    }
  }
}

// ---------------------------------------------------------------------------
extern "C" void kernel_launch(void* const* d_in, const int* in_sizes, int n_in,
                              void* d_out, int out_size, void* d_ws,
                              size_t ws_size, hipStream_t stream) {
  const float* query  = (const float*)d_in[0];
  const float* value  = (const float*)d_in[1];
  const float* refpts = (const float*)d_in[2];
  const float* W_off  = (const float*)d_in[3];
  const float* b_off  = (const float*)d_in[4];
  const float* W_attn = (const float*)d_in[5];
  const float* b_attn = (const float*)d_in[6];
  const float* W_val  = (const float*)d_in[7];
  const float* b_val  = (const float*)d_in[8];
  const float* W_out  = (const float*)d_in[9];
  const float* b_out  = (const float*)d_in[10];
  float* out = (float*)d_out;

  char* ws = (char*)d_ws;
  unsigned short* vbh = (unsigned short*)ws;                   // 27,226,112 B
  float* locbuf = (float*)(ws + 27226112);                     // 24,576,000 B
  float* awbuf = (float*)(ws + 51802112);                      // 12,288,000 B
  unsigned short* sampledb = (unsigned short*)(ws + 64090112); // 12,288,000 B
  unsigned short* Wt_val = (unsigned short*)(ws + 76378112);   //    131,072 B
  unsigned short* Wt_qcat = (unsigned short*)(ws + 76509184);  //    196,608 B
  unsigned short* Wt_out = (unsigned short*)(ws + 76705792);   //    131,072 B

  wtrans_kernel<<<896, 256, 0, stream>>>(W_val, W_off, W_attn, W_out, Wt_val,
                                         Wt_qcat, Wt_out);
  vproj_kernel<<<832, 256, 0, stream>>>(value, Wt_val, b_val, vbh);
  qproj_kernel<<<576, 256, 0, stream>>>(query, Wt_qcat, refpts, b_off, b_attn,
                                        locbuf, awbuf);
  sample_kernel<<<BS * NQ * NH / 4, 256, 0, stream>>>(vbh, locbuf, awbuf,
                                                      sampledb);
  oproj_kernel<<<384, 256, 0, stream>>>(sampledb, Wt_out, b_out, query, out);
}

// Round 5
// 258.831 us; speedup vs baseline: 3.1187x; 1.0144x over previous
//
#include <hip/hip_runtime.h>
#include <hip/hip_bf16.h>

#define BS 4
#define NQ 6000
#define NV 13294
#define NH 8
#define HD 32
#define EMB 256
#define MV (BS * NV)  // 53176
#define MQ (BS * NQ)  // 24000

typedef __attribute__((ext_vector_type(8))) short short8;
typedef __attribute__((ext_vector_type(4))) float floatx4;
typedef __attribute__((ext_vector_type(2))) float floatx2;

__device__ __constant__ float LVL_DIM[4] = {100.f, 50.f, 25.f, 13.f};

__device__ inline unsigned short bf16bits(float f) {
  __hip_bfloat16 h = __float2bfloat16(f);
  return *reinterpret_cast<unsigned short*>(&h);
}
__device__ inline float bflo(unsigned int u) { return __uint_as_float(u << 16); }
__device__ inline float bfhi(unsigned int u) { return __uint_as_float(u & 0xffff0000u); }
__device__ inline floatx2 unpk(unsigned int u) {
  floatx2 r;
  r.x = __uint_as_float(u << 16);
  r.y = __uint_as_float(u & 0xffff0000u);
  return r;
}

#define LDS_STRIDE 40  // 32 + 8 pad: conflict-free ds_read_b128

// ---------------------------------------------------------------------------
// Weight transpose + bf16 convert: Wt[n][k] = bf16(W[k][n]).
// ---------------------------------------------------------------------------
__global__ __launch_bounds__(256) void wtrans_kernel(
    const float* __restrict__ W_val, const float* __restrict__ W_off,
    const float* __restrict__ W_attn, const float* __restrict__ W_out,
    unsigned short* __restrict__ Wt_val, unsigned short* __restrict__ Wt_qcat,
    unsigned short* __restrict__ Wt_out) {
  const int b = blockIdx.x, k = threadIdx.x;
  if (b < 256) {
    Wt_val[b * EMB + k] = bf16bits(W_val[k * 256 + b]);
  } else if (b < 640) {
    const int n = b - 256;
    float v = (n < 256) ? W_off[k * 256 + n] : W_attn[k * 128 + (n - 256)];
    Wt_qcat[n * EMB + k] = bf16bits(v);
  } else {
    const int n = b - 640;
    Wt_out[n * EMB + k] = bf16bits(W_out[k * 256 + n]);
  }
}

// ---------------------------------------------------------------------------
// MFMA-GEMM core: 128x128 tile, 4 waves (64x64 each), 4x4 of
// mfma_f32_16x16x32_bf16, BK=32, register-prefetch pipelined K-loop.
// ---------------------------------------------------------------------------
__device__ inline void loadA_f32(const float* __restrict__ A, int M, int m0,
                                 int k0, int tid, float4 ra[4]) {
  const int r = tid >> 1, half = tid & 1;
  const int row = m0 + r;
  if (row < M) {
    const float* src = A + (size_t)row * EMB + k0 + half * 16;
#pragma unroll
    for (int j = 0; j < 4; ++j) ra[j] = *(const float4*)(src + 4 * j);
  } else {
#pragma unroll
    for (int j = 0; j < 4; ++j) ra[j] = make_float4(0.f, 0.f, 0.f, 0.f);
  }
}
__device__ inline void storeA_lds(unsigned short* lds, int tid,
                                  const float4 ra[4]) {
  const int r = tid >> 1, half = tid & 1;
  unsigned short* dst = lds + r * LDS_STRIDE + half * 16;
#pragma unroll
  for (int j = 0; j < 4; ++j) {
    ushort4 u;
    u.x = bf16bits(ra[j].x);
    u.y = bf16bits(ra[j].y);
    u.z = bf16bits(ra[j].z);
    u.w = bf16bits(ra[j].w);
    *(ushort4*)(dst + 4 * j) = u;
  }
}
__device__ inline void loadB_bf16(const unsigned short* __restrict__ B, int M,
                                  int n0, int k0, int tid, uint4 rb[2]) {
  const int r = tid >> 1, half = tid & 1;
  const int row = n0 + r;
  if (row < M) {
    const unsigned short* src = B + (size_t)row * EMB + k0 + half * 16;
    rb[0] = *(const uint4*)(src);
    rb[1] = *(const uint4*)(src + 8);
  } else {
    rb[0] = rb[1] = make_uint4(0, 0, 0, 0);
  }
}
__device__ inline void storeB_lds(unsigned short* lds, int tid,
                                  const uint4 rb[2]) {
  const int r = tid >> 1, half = tid & 1;
  unsigned short* dst = lds + r * LDS_STRIDE + half * 16;
  *(uint4*)(dst) = rb[0];
  *(uint4*)(dst + 8) = rb[1];
}

__device__ inline void mfma_step(const unsigned short* ldsA,
                                 const unsigned short* ldsB, int wm, int wn,
                                 int lane, floatx4 acc[4][4]) {
  const unsigned short* ap =
      ldsA + (wm * 64 + (lane & 15)) * LDS_STRIDE + (lane >> 4) * 8;
  const unsigned short* bp =
      ldsB + (wn * 64 + (lane & 15)) * LDS_STRIDE + (lane >> 4) * 8;
  short8 af[4], bfr[4];
#pragma unroll
  for (int t = 0; t < 4; ++t) {
    af[t] = *(const short8*)(ap + t * 16 * LDS_STRIDE);
    bfr[t] = *(const short8*)(bp + t * 16 * LDS_STRIDE);
  }
#pragma unroll
  for (int mt = 0; mt < 4; ++mt)
#pragma unroll
    for (int nt = 0; nt < 4; ++nt)
      acc[mt][nt] = __builtin_amdgcn_mfma_f32_16x16x32_bf16(af[mt], bfr[nt],
                                                            acc[mt][nt], 0, 0, 0);
}

// Pipelined K-loop, A in fp32 (converted during staging).
__device__ inline void gemm_loop_f32A(const float* __restrict__ A, int M,
                                      int m0, const unsigned short* __restrict__ B,
                                      int NB, int n0, unsigned short* ldsA,
                                      unsigned short* ldsB, int tid, int wm,
                                      int wn, int lane, floatx4 acc[4][4]) {
  float4 ra[4];
  uint4 rb[2];
  loadA_f32(A, M, m0, 0, tid, ra);
  loadB_bf16(B, NB, n0, 0, tid, rb);
#pragma unroll
  for (int k = 0; k < 8; ++k) {
    storeA_lds(ldsA, tid, ra);
    storeB_lds(ldsB, tid, rb);
    __syncthreads();
    if (k < 7) {
      loadA_f32(A, M, m0, (k + 1) * 32, tid, ra);
      loadB_bf16(B, NB, n0, (k + 1) * 32, tid, rb);
    }
    mfma_step(ldsA, ldsB, wm, wn, lane, acc);
    __syncthreads();
  }
}

// Pipelined K-loop, A already bf16.
__device__ inline void gemm_loop_bf16A(const unsigned short* __restrict__ A,
                                       int M, int m0,
                                       const unsigned short* __restrict__ B,
                                       int NB, int n0, unsigned short* ldsA,
                                       unsigned short* ldsB, int tid, int wm,
                                       int wn, int lane, floatx4 acc[4][4]) {
  uint4 ra[2], rb[2];
  loadB_bf16(A, M, m0, 0, tid, ra);
  loadB_bf16(B, NB, n0, 0, tid, rb);
#pragma unroll
  for (int k = 0; k < 8; ++k) {
    storeB_lds(ldsA, tid, ra);
    storeB_lds(ldsB, tid, rb);
    __syncthreads();
    if (k < 7) {
      loadB_bf16(A, M, m0, (k + 1) * 32, tid, ra);
      loadB_bf16(B, NB, n0, (k + 1) * 32, tid, rb);
    }
    mfma_step(ldsA, ldsB, wm, wn, lane, acc);
    __syncthreads();
  }
}

// ---------------------------------------------------------------------------
// Fused K1+K2: blocks [0,832): value proj; [832,1408): offset/attn proj.
// Sibling swizzle within each range keeps same-A tiles on one XCD slot.
// ---------------------------------------------------------------------------
__global__ __launch_bounds__(256) void vqproj_kernel(
    const float* __restrict__ value, const unsigned short* __restrict__ Wt_val,
    const float* __restrict__ b_val, unsigned short* __restrict__ vbh,
    const float* __restrict__ query, const unsigned short* __restrict__ Wt_qcat,
    const float* __restrict__ refpts, const float* __restrict__ b_off,
    const float* __restrict__ b_attn, float* __restrict__ locbuf,
    float* __restrict__ awbuf) {
  __shared__ unsigned short ldsA[128 * LDS_STRIDE];
  __shared__ unsigned short ldsB[128 * LDS_STRIDE];
  const int tid = threadIdx.x, lane = tid & 63, w = tid >> 6;
  const int wm = w >> 1, wn = w & 1;
  floatx4 acc[4][4];
  const floatx4 zero = {0.f, 0.f, 0.f, 0.f};
#pragma unroll
  for (int i2 = 0; i2 < 4; i2++)
#pragma unroll
    for (int j = 0; j < 4; j++) acc[i2][j] = zero;
  const int quad = lane >> 4, cl = lane & 15;

  if (blockIdx.x < 832) {
    // ---- value projection ----
    const int chunk = blockIdx.x >> 4, i = blockIdx.x & 15;
    const int m0 = (chunk * 8 + (i & 7)) * 128;
    const int n0 = (i >> 3) * 128;
    gemm_loop_f32A(value, MV, m0, Wt_val, 256, n0, ldsA, ldsB, tid, wm, wn,
                   lane, acc);
#pragma unroll
    for (int mt = 0; mt < 4; ++mt) {
#pragma unroll
      for (int r = 0; r < 4; ++r) {
        const int row = m0 + wm * 64 + mt * 16 + quad * 4 + r;
        if (row < MV) {
          const int b = row / NV, n = row - b * NV;
#pragma unroll
          for (int nt = 0; nt < 4; ++nt) {
            const int c = n0 + wn * 64 + nt * 16 + cl;
            const int h = c >> 5, d = c & 31;
            vbh[(((size_t)(b * NH + h)) * NV + n) * HD + d] =
                bf16bits(acc[mt][nt][r] + b_val[c]);
          }
        }
      }
    }
  } else {
    // ---- query (offset|attn) projection ----
    const int bid = blockIdx.x - 832;
    const int chunk = bid / 24, i = bid % 24;
    const int m_idx = chunk * 8 + (i & 7);
    if (m_idx >= 188) return;
    const int m0 = m_idx * 128;
    const int n0 = (i >> 3) * 128;
    gemm_loop_f32A(query, MQ, m0, Wt_qcat, 384, n0, ldsA, ldsB, tid, wm, wn,
                   lane, acc);
    if (n0 < 256) {  // offset region
#pragma unroll
      for (int mt = 0; mt < 4; ++mt) {
#pragma unroll
        for (int r = 0; r < 4; ++r) {
          const int row = m0 + wm * 64 + mt * 16 + quad * 4 + r;
          if (row < MQ) {
#pragma unroll
            for (int nt = 0; nt < 4; ++nt) {
              const int c = n0 + wn * 64 + nt * 16 + cl;
              const int xy = c & 1, l = (c >> 3) & 3;
              const float dim = LVL_DIM[l];
              const float ref = refpts[(size_t)row * 8 + l * 2 + xy];
              locbuf[(size_t)row * 256 + c] =
                  ref * dim + acc[mt][nt][r] + b_off[c] - 0.5f;
            }
          }
        }
      }
    } else {  // attn region: softmax over 16 consecutive cols
#pragma unroll
      for (int mt = 0; mt < 4; ++mt) {
#pragma unroll
        for (int r = 0; r < 4; ++r) {
          const int row = m0 + wm * 64 + mt * 16 + quad * 4 + r;
          if (row < MQ) {
#pragma unroll
            for (int nt = 0; nt < 4; ++nt) {
              const int ca = wn * 64 + nt * 16 + cl;
              float v = acc[mt][nt][r] + b_attn[ca];
              float m = v;
              m = fmaxf(m, __shfl_xor(m, 1));
              m = fmaxf(m, __shfl_xor(m, 2));
              m = fmaxf(m, __shfl_xor(m, 4));
              m = fmaxf(m, __shfl_xor(m, 8));
              float e = __expf(v - m);
              float s = e;
              s += __shfl_xor(s, 1);
              s += __shfl_xor(s, 2);
              s += __shfl_xor(s, 4);
              s += __shfl_xor(s, 8);
              awbuf[(size_t)row * 128 + ca] = e / s;
            }
          }
        }
      }
    }
  }
}

// ---------------------------------------------------------------------------
// K3: bilinear sampling. 16 sample-groups x 4 lanes; lane owns 8 dims.
// XCD-pinned: blockIdx&7 selects 4 (b,h) slices (3.4 MB < 4 MB per-XCD L2).
// ---------------------------------------------------------------------------
__global__ __launch_bounds__(256) void sample_kernel(
    const unsigned short* __restrict__ vbh, const float* __restrict__ locbuf,
    const float* __restrict__ awbuf, unsigned short* __restrict__ sampledb) {
  const int blk = blockIdx.x;
  const int t = blk >> 3;
  const int quarter = t / 1500;
  const int j = t - quarter * 1500;
  const int slice = (blk & 7) * 4 + quarter;  // b*8+h
  const int h = slice & 7;
  const int w = threadIdx.x >> 6;
  const int lane = threadIdx.x & 63;
  const int row = (slice >> 3) * NQ + j * 4 + w;  // b*NQ + q
  const int g = lane >> 2;  // sample 0..15: l = g>>2, p = g&3
  const int d8 = lane & 3;  // dim octet
  const int l = g >> 2;

  const int W_ = (l < 2) ? ((l == 0) ? 100 : 50) : ((l == 2) ? 25 : 13);
  const int START = (l < 2) ? ((l == 0) ? 0 : 10000) : ((l == 2) ? 12500 : 13125);

  const float2 xy = *(const float2*)(locbuf + (size_t)row * 256 + h * 32 + g * 2);
  const float wgt = awbuf[(size_t)row * 128 + h * 16 + g];

  const float fx = floorf(xy.x), fy = floorf(xy.y);
  const int x0 = (int)fx, y0 = (int)fy;
  const float wx1 = xy.x - fx, wy1 = xy.y - fy;
  const float wx0 = 1.f - wx1, wy0 = 1.f - wy1;
  const int x0c = min(max(x0, 0), W_ - 1), x1c = min(max(x0 + 1, 0), W_ - 1);
  const int y0c = min(max(y0, 0), W_ - 1), y1c = min(max(y0 + 1, 0), W_ - 1);
  const float mx0 = ((unsigned)x0 < (unsigned)W_) ? wx0 : 0.f;
  const float mx1 = ((unsigned)(x0 + 1) < (unsigned)W_) ? wx1 : 0.f;
  const float my0 = ((unsigned)y0 < (unsigned)W_) ? wy0 : 0.f;
  const float my1 = ((unsigned)(y0 + 1) < (unsigned)W_) ? wy1 : 0.f;
  const float wy0w = wgt * my0, wy1w = wgt * my1;
  const float w00 = wy0w * mx0, w01 = wy0w * mx1;
  const float w10 = wy1w * mx0, w11 = wy1w * mx1;
  floatx2 w00v = {w00, w00}, w01v = {w01, w01};
  floatx2 w10v = {w10, w10}, w11v = {w11, w11};

  const unsigned int* base =
      (const unsigned int*)vbh + ((size_t)slice * NV + START) * 16 + d8 * 4;
  const int rb0 = y0c * W_, rb1 = y1c * W_;
  const uint4 u00 = *(const uint4*)(base + (size_t)(rb0 + x0c) * 16);
  const uint4 u01 = *(const uint4*)(base + (size_t)(rb0 + x1c) * 16);
  const uint4 u10 = *(const uint4*)(base + (size_t)(rb1 + x0c) * 16);
  const uint4 u11 = *(const uint4*)(base + (size_t)(rb1 + x1c) * 16);

  const unsigned int* p00 = &u00.x;
  const unsigned int* p01 = &u01.x;
  const unsigned int* p10 = &u10.x;
  const unsigned int* p11 = &u11.x;
  floatx2 a2[4];
#pragma unroll
  for (int k = 0; k < 4; ++k) {
    floatx2 s = w00v * unpk(p00[k]);
    s += w01v * unpk(p01[k]);
    s += w10v * unpk(p10[k]);
    s += w11v * unpk(p11[k]);
    a2[k] = s;
  }

  float a[8];
#pragma unroll
  for (int k = 0; k < 4; ++k) {
    a[2 * k] = a2[k].x;
    a[2 * k + 1] = a2[k].y;
  }
#pragma unroll
  for (int k = 0; k < 8; ++k) {
    a[k] += __shfl_xor(a[k], 4);
    a[k] += __shfl_xor(a[k], 8);
    a[k] += __shfl_xor(a[k], 16);
    a[k] += __shfl_xor(a[k], 32);
  }

  if (g == 0) {
    uint4 o;
    o.x = (unsigned)bf16bits(a[0]) | ((unsigned)bf16bits(a[1]) << 16);
    o.y = (unsigned)bf16bits(a[2]) | ((unsigned)bf16bits(a[3]) << 16);
    o.z = (unsigned)bf16bits(a[4]) | ((unsigned)bf16bits(a[5]) << 16);
    o.w = (unsigned)bf16bits(a[6]) | ((unsigned)bf16bits(a[7]) << 16);
    *(uint4*)(sampledb + (size_t)row * EMB + h * 32 + d8 * 8) = o;
  }
}

// ---------------------------------------------------------------------------
// K4: out = sampled @ W_out + b_out + query (residual fused), pipelined.
// ---------------------------------------------------------------------------
__global__ __launch_bounds__(256) void oproj_kernel(
    const unsigned short* __restrict__ sampledb,
    const unsigned short* __restrict__ Wt, const float* __restrict__ b_out,
    const float* __restrict__ query, float* __restrict__ out) {
  __shared__ unsigned short ldsA[128 * LDS_STRIDE];
  __shared__ unsigned short ldsB[128 * LDS_STRIDE];
  const int tid = threadIdx.x, lane = tid & 63, w = tid >> 6;
  const int wm = w >> 1, wn = w & 1;
  const int chunk = blockIdx.x >> 4, i = blockIdx.x & 15;
  const int m_idx = chunk * 8 + (i & 7);
  if (m_idx >= 188) return;
  const int m0 = m_idx * 128;
  const int n0 = (i >> 3) * 128;
  floatx4 acc[4][4];
  const floatx4 zero = {0.f, 0.f, 0.f, 0.f};
#pragma unroll
  for (int i2 = 0; i2 < 4; i2++)
#pragma unroll
    for (int j = 0; j < 4; j++) acc[i2][j] = zero;

  gemm_loop_bf16A(sampledb, MQ, m0, Wt, 256, n0, ldsA, ldsB, tid, wm, wn, lane,
                  acc);

  const int quad = lane >> 4, cl = lane & 15;
#pragma unroll
  for (int mt = 0; mt < 4; ++mt) {
#pragma unroll
    for (int r = 0; r < 4; ++r) {
      const int row = m0 + wm * 64 + mt * 16 + quad * 4 + r;
      if (row < MQ) {
#pragma unroll
        for (int nt = 0; nt < 4; ++nt) {
          const int c = n0 + wn * 64 + nt * 16 + cl;
          out[(size_t)row * EMB + c] =
              acc[mt][nt][r] + b_out[c] + query[(size_t)row * EMB + c];
        }
      }
    }
  }
}

// ---------------------------------------------------------------------------
extern "C" void kernel_launch(void* const* d_in, const int* in_sizes, int n_in,
                              void* d_out, int out_size, void* d_ws,
                              size_t ws_size, hipStream_t stream) {
  const float* query  = (const float*)d_in[0];
  const float* value  = (const float*)d_in[1];
  const float* refpts = (const float*)d_in[2];
  const float* W_off  = (const float*)d_in[3];
  const float* b_off  = (const float*)d_in[4];
  const float* W_attn = (const float*)d_in[5];
  const float* b_attn = (const float*)d_in[6];
  const float* W_val  = (const float*)d_in[7];
  const float* b_val  = (const float*)d_in[8];
  const float* W_out  = (const float*)d_in[9];
  const float* b_out  = (const float*)d_in[10];
  float* out = (float*)d_out;

  char* ws = (char*)d_ws;
  unsigned short* vbh = (unsigned short*)ws;                   // 27,226,112 B
  float* locbuf = (float*)(ws + 27226112);                     // 24,576,000 B
  float* awbuf = (float*)(ws + 51802112);                      // 12,288,000 B
  unsigned short* sampledb = (unsigned short*)(ws + 64090112); // 12,288,000 B
  unsigned short* Wt_val = (unsigned short*)(ws + 76378112);   //    131,072 B
  unsigned short* Wt_qcat = (unsigned short*)(ws + 76509184);  //    196,608 B
  unsigned short* Wt_out = (unsigned short*)(ws + 76705792);   //    131,072 B

  wtrans_kernel<<<896, 256, 0, stream>>>(W_val, W_off, W_attn, W_out, Wt_val,
                                         Wt_qcat, Wt_out);
  vqproj_kernel<<<1408, 256, 0, stream>>>(value, Wt_val, b_val, vbh, query,
                                          Wt_qcat, refpts, b_off, b_attn,
                                          locbuf, awbuf);
  sample_kernel<<<BS * NQ * NH / 4, 256, 0, stream>>>(vbh, locbuf, awbuf,
                                                      sampledb);
  oproj_kernel<<<384, 256, 0, stream>>>(sampledb, Wt_out, b_out, query, out);
}

// Round 6
// 247.661 us; speedup vs baseline: 3.2594x; 1.0451x over previous
//
#include <hip/hip_runtime.h>
#include <hip/hip_bf16.h>

#define BS 4
#define NQ 6000
#define NV 13294
#define NH 8
#define HD 32
#define EMB 256
#define MV (BS * NV)  // 53176
#define MQ (BS * NQ)  // 24000

typedef __attribute__((ext_vector_type(8))) short short8;
typedef __attribute__((ext_vector_type(4))) float floatx4;

__device__ __constant__ float LVL_DIM[4] = {100.f, 50.f, 25.f, 13.f};

__device__ inline unsigned short bf16bits(float f) {
  __hip_bfloat16 h = __float2bfloat16(f);
  return *reinterpret_cast<unsigned short*>(&h);
}
__device__ inline float bflo(unsigned int u) { return __uint_as_float(u << 16); }
__device__ inline float bfhi(unsigned int u) { return __uint_as_float(u & 0xffff0000u); }

#define LDSTR 72  // 64 + 8 pad: <=2-way bank aliasing for ds_read_b128

// ---------------------------------------------------------------------------
// Weight transpose + bf16 convert: Wt[n][k] = bf16(W[k][n]).
// ---------------------------------------------------------------------------
__global__ __launch_bounds__(256) void wtrans_kernel(
    const float* __restrict__ W_val, const float* __restrict__ W_off,
    const float* __restrict__ W_attn, const float* __restrict__ W_out,
    unsigned short* __restrict__ Wt_val, unsigned short* __restrict__ Wt_qcat,
    unsigned short* __restrict__ Wt_out) {
  const int b = blockIdx.x, k = threadIdx.x;
  if (b < 256) {
    Wt_val[b * EMB + k] = bf16bits(W_val[k * 256 + b]);
  } else if (b < 640) {
    const int n = b - 256;
    float v = (n < 256) ? W_off[k * 256 + n] : W_attn[k * 128 + (n - 256)];
    Wt_qcat[n * EMB + k] = bf16bits(v);
  } else {
    const int n = b - 640;
    Wt_out[n * EMB + k] = bf16bits(W_out[k * 256 + n]);
  }
}

// ---------------------------------------------------------------------------
// MFMA-GEMM core: 128x128 tile, 4 waves (64x64 each), BK=64 (4 K-iters,
// 32 MFMA per barrier), register-prefetch pipelined.
// ---------------------------------------------------------------------------
__device__ inline void loadA_f32(const float* __restrict__ A, int M, int m0,
                                 int k0, int tid, float4 ra[8]) {
  const int r = tid >> 1, half = tid & 1;
  const int row = m0 + r;
  if (row < M) {
    const float* src = A + (size_t)row * EMB + k0 + half * 32;
#pragma unroll
    for (int j = 0; j < 8; ++j) ra[j] = *(const float4*)(src + 4 * j);
  } else {
#pragma unroll
    for (int j = 0; j < 8; ++j) ra[j] = make_float4(0.f, 0.f, 0.f, 0.f);
  }
}
__device__ inline void storeA_lds(unsigned short* lds, int tid,
                                  const float4 ra[8]) {
  const int r = tid >> 1, half = tid & 1;
  unsigned short* dst = lds + r * LDSTR + half * 32;
#pragma unroll
  for (int j = 0; j < 8; ++j) {
    ushort4 u;
    u.x = bf16bits(ra[j].x);
    u.y = bf16bits(ra[j].y);
    u.z = bf16bits(ra[j].z);
    u.w = bf16bits(ra[j].w);
    *(ushort4*)(dst + 4 * j) = u;
  }
}
__device__ inline void loadB_bf16(const unsigned short* __restrict__ B, int M,
                                  int n0, int k0, int tid, uint4 rb[4]) {
  const int r = tid >> 1, half = tid & 1;
  const int row = n0 + r;
  if (row < M) {
    const unsigned short* src = B + (size_t)row * EMB + k0 + half * 32;
#pragma unroll
    for (int j = 0; j < 4; ++j) rb[j] = *(const uint4*)(src + 8 * j);
  } else {
#pragma unroll
    for (int j = 0; j < 4; ++j) rb[j] = make_uint4(0, 0, 0, 0);
  }
}
__device__ inline void storeB_lds(unsigned short* lds, int tid,
                                  const uint4 rb[4]) {
  const int r = tid >> 1, half = tid & 1;
  unsigned short* dst = lds + r * LDSTR + half * 32;
#pragma unroll
  for (int j = 0; j < 4; ++j) *(uint4*)(dst + 8 * j) = rb[j];
}

__device__ inline void mfma_step(const unsigned short* ldsA,
                                 const unsigned short* ldsB, int wm, int wn,
                                 int lane, int ksub, floatx4 acc[4][4]) {
  const unsigned short* ap =
      ldsA + (wm * 64 + (lane & 15)) * LDSTR + ksub + (lane >> 4) * 8;
  const unsigned short* bp =
      ldsB + (wn * 64 + (lane & 15)) * LDSTR + ksub + (lane >> 4) * 8;
  short8 af[4], bfr[4];
#pragma unroll
  for (int t = 0; t < 4; ++t) {
    af[t] = *(const short8*)(ap + t * 16 * LDSTR);
    bfr[t] = *(const short8*)(bp + t * 16 * LDSTR);
  }
#pragma unroll
  for (int mt = 0; mt < 4; ++mt)
#pragma unroll
    for (int nt = 0; nt < 4; ++nt)
      acc[mt][nt] = __builtin_amdgcn_mfma_f32_16x16x32_bf16(af[mt], bfr[nt],
                                                            acc[mt][nt], 0, 0, 0);
}

__device__ inline void gemm_loop_f32A(const float* __restrict__ A, int M,
                                      int m0, const unsigned short* __restrict__ B,
                                      int NB, int n0, unsigned short* ldsA,
                                      unsigned short* ldsB, int tid, int wm,
                                      int wn, int lane, floatx4 acc[4][4]) {
  float4 ra[8];
  uint4 rb[4];
  loadA_f32(A, M, m0, 0, tid, ra);
  loadB_bf16(B, NB, n0, 0, tid, rb);
#pragma unroll
  for (int k = 0; k < 4; ++k) {
    storeA_lds(ldsA, tid, ra);
    storeB_lds(ldsB, tid, rb);
    __syncthreads();
    if (k < 3) {
      loadA_f32(A, M, m0, (k + 1) * 64, tid, ra);
      loadB_bf16(B, NB, n0, (k + 1) * 64, tid, rb);
    }
    mfma_step(ldsA, ldsB, wm, wn, lane, 0, acc);
    mfma_step(ldsA, ldsB, wm, wn, lane, 32, acc);
    __syncthreads();
  }
}

__device__ inline void gemm_loop_bf16A(const unsigned short* __restrict__ A,
                                       int M, int m0,
                                       const unsigned short* __restrict__ B,
                                       int NB, int n0, unsigned short* ldsA,
                                       unsigned short* ldsB, int tid, int wm,
                                       int wn, int lane, floatx4 acc[4][4]) {
  uint4 ra[4], rb[4];
  loadB_bf16(A, M, m0, 0, tid, ra);
  loadB_bf16(B, NB, n0, 0, tid, rb);
#pragma unroll
  for (int k = 0; k < 4; ++k) {
    storeB_lds(ldsA, tid, ra);
    storeB_lds(ldsB, tid, rb);
    __syncthreads();
    if (k < 3) {
      loadB_bf16(A, M, m0, (k + 1) * 64, tid, ra);
      loadB_bf16(B, NB, n0, (k + 1) * 64, tid, rb);
    }
    mfma_step(ldsA, ldsB, wm, wn, lane, 0, acc);
    mfma_step(ldsA, ldsB, wm, wn, lane, 32, acc);
    __syncthreads();
  }
}

// ---------------------------------------------------------------------------
// Fused K1+K2: blocks [0,832): value proj; [832,1408): offset/attn proj.
// ---------------------------------------------------------------------------
__global__ __launch_bounds__(256, 2) void vqproj_kernel(
    const float* __restrict__ value, const unsigned short* __restrict__ Wt_val,
    const float* __restrict__ b_val, unsigned short* __restrict__ vbh,
    const float* __restrict__ query, const unsigned short* __restrict__ Wt_qcat,
    const float* __restrict__ refpts, const float* __restrict__ b_off,
    const float* __restrict__ b_attn, float* __restrict__ locbuf,
    float* __restrict__ awbuf) {
  __shared__ unsigned short ldsA[128 * LDSTR];
  __shared__ unsigned short ldsB[128 * LDSTR];
  const int tid = threadIdx.x, lane = tid & 63, w = tid >> 6;
  const int wm = w >> 1, wn = w & 1;
  floatx4 acc[4][4];
  const floatx4 zero = {0.f, 0.f, 0.f, 0.f};
#pragma unroll
  for (int i2 = 0; i2 < 4; i2++)
#pragma unroll
    for (int j = 0; j < 4; j++) acc[i2][j] = zero;
  const int quad = lane >> 4, cl = lane & 15;

  if (blockIdx.x < 832) {
    const int chunk = blockIdx.x >> 4, i = blockIdx.x & 15;
    const int m0 = (chunk * 8 + (i & 7)) * 128;
    const int n0 = (i >> 3) * 128;
    gemm_loop_f32A(value, MV, m0, Wt_val, 256, n0, ldsA, ldsB, tid, wm, wn,
                   lane, acc);
#pragma unroll
    for (int mt = 0; mt < 4; ++mt) {
#pragma unroll
      for (int r = 0; r < 4; ++r) {
        const int row = m0 + wm * 64 + mt * 16 + quad * 4 + r;
        if (row < MV) {
          const int b = row / NV, n = row - b * NV;
#pragma unroll
          for (int nt = 0; nt < 4; ++nt) {
            const int c = n0 + wn * 64 + nt * 16 + cl;
            const int h = c >> 5, d = c & 31;
            vbh[(((size_t)(b * NH + h)) * NV + n) * HD + d] =
                bf16bits(acc[mt][nt][r] + b_val[c]);
          }
        }
      }
    }
  } else {
    const int bid = blockIdx.x - 832;
    const int chunk = bid / 24, i = bid % 24;
    const int m_idx = chunk * 8 + (i & 7);
    if (m_idx >= 188) return;
    const int m0 = m_idx * 128;
    const int n0 = (i >> 3) * 128;
    gemm_loop_f32A(query, MQ, m0, Wt_qcat, 384, n0, ldsA, ldsB, tid, wm, wn,
                   lane, acc);
    if (n0 < 256) {  // offset region
#pragma unroll
      for (int mt = 0; mt < 4; ++mt) {
#pragma unroll
        for (int r = 0; r < 4; ++r) {
          const int row = m0 + wm * 64 + mt * 16 + quad * 4 + r;
          if (row < MQ) {
#pragma unroll
            for (int nt = 0; nt < 4; ++nt) {
              const int c = n0 + wn * 64 + nt * 16 + cl;
              const int xy = c & 1, l = (c >> 3) & 3;
              const float dim = LVL_DIM[l];
              const float ref = refpts[(size_t)row * 8 + l * 2 + xy];
              locbuf[(size_t)row * 256 + c] =
                  ref * dim + acc[mt][nt][r] + b_off[c] - 0.5f;
            }
          }
        }
      }
    } else {  // attn region: softmax over 16 consecutive cols
#pragma unroll
      for (int mt = 0; mt < 4; ++mt) {
#pragma unroll
        for (int r = 0; r < 4; ++r) {
          const int row = m0 + wm * 64 + mt * 16 + quad * 4 + r;
          if (row < MQ) {
#pragma unroll
            for (int nt = 0; nt < 4; ++nt) {
              const int ca = wn * 64 + nt * 16 + cl;
              float v = acc[mt][nt][r] + b_attn[ca];
              float m = v;
              m = fmaxf(m, __shfl_xor(m, 1));
              m = fmaxf(m, __shfl_xor(m, 2));
              m = fmaxf(m, __shfl_xor(m, 4));
              m = fmaxf(m, __shfl_xor(m, 8));
              float e = __expf(v - m);
              float s = e;
              s += __shfl_xor(s, 1);
              s += __shfl_xor(s, 2);
              s += __shfl_xor(s, 4);
              s += __shfl_xor(s, 8);
              awbuf[(size_t)row * 128 + ca] = e / s;
            }
          }
        }
      }
    }
  }
}

// ---------------------------------------------------------------------------
// K3: bilinear sampling. Each wave: 2 rows of one (b,h) slice;
// 16 sample-groups x 4 lanes, lane owns 8 dims (dwordx4 corners, 8 loads in
// flight across the two rows). Reduce-scatter finish: lane ends owning one
// dim of one row. XCD-pinned via blockIdx&7.
// ---------------------------------------------------------------------------
__global__ __launch_bounds__(256, 4) void sample_kernel(
    const unsigned short* __restrict__ vbh, const float* __restrict__ locbuf,
    const float* __restrict__ awbuf, unsigned short* __restrict__ sampledb) {
  const int blk = blockIdx.x;
  const int t = blk >> 3;           // [0, 3000)
  const int quarter = t / 750;
  const int j = t - quarter * 750;  // [0, 750)
  const int slice = (blk & 7) * 4 + quarter;  // b*8 + h
  const int h = slice & 7;
  const int w = threadIdx.x >> 6;
  const int lane = threadIdx.x & 63;
  const int r0 = (slice >> 3) * NQ + j * 8 + w * 2;  // rows r0, r0+1
  const int g = lane >> 2;  // sample 0..15: l = g>>2, p = g&3
  const int d8 = lane & 3;  // dim octet
  const int l = g >> 2;

  const int W_ = (l < 2) ? ((l == 0) ? 100 : 50) : ((l == 2) ? 25 : 13);
  const int START = (l < 2) ? ((l == 0) ? 0 : 10000) : ((l == 2) ? 12500 : 13125);
  const unsigned int* base =
      (const unsigned int*)vbh + ((size_t)slice * NV + START) * 16 + d8 * 4;

  float acc0[8], acc1[8];
#pragma unroll
  for (int rr = 0; rr < 2; ++rr) {
    const int row = r0 + rr;
    float* a = rr ? acc1 : acc0;
    const float2 xy =
        *(const float2*)(locbuf + (size_t)row * 256 + h * 32 + g * 2);
    const float wgt = awbuf[(size_t)row * 128 + h * 16 + g];

    const float fx = floorf(xy.x), fy = floorf(xy.y);
    const int x0 = (int)fx, y0 = (int)fy;
    const float wx1 = xy.x - fx, wy1 = xy.y - fy;
    const float wx0 = 1.f - wx1, wy0 = 1.f - wy1;
    const int x0c = min(max(x0, 0), W_ - 1), x1c = min(max(x0 + 1, 0), W_ - 1);
    const int y0c = min(max(y0, 0), W_ - 1), y1c = min(max(y0 + 1, 0), W_ - 1);
    const float mx0 = ((unsigned)x0 < (unsigned)W_) ? wx0 : 0.f;
    const float mx1 = ((unsigned)(x0 + 1) < (unsigned)W_) ? wx1 : 0.f;
    const float my0 = ((unsigned)y0 < (unsigned)W_) ? wy0 : 0.f;
    const float my1 = ((unsigned)(y0 + 1) < (unsigned)W_) ? wy1 : 0.f;
    const float wy0w = wgt * my0, wy1w = wgt * my1;
    const float w00 = wy0w * mx0, w01 = wy0w * mx1;
    const float w10 = wy1w * mx0, w11 = wy1w * mx1;

    const int rb0 = y0c * W_, rb1 = y1c * W_;
    const uint4 u00 = *(const uint4*)(base + (size_t)(rb0 + x0c) * 16);
    const uint4 u01 = *(const uint4*)(base + (size_t)(rb0 + x1c) * 16);
    const uint4 u10 = *(const uint4*)(base + (size_t)(rb1 + x0c) * 16);
    const uint4 u11 = *(const uint4*)(base + (size_t)(rb1 + x1c) * 16);
    const unsigned int* p00 = &u00.x;
    const unsigned int* p01 = &u01.x;
    const unsigned int* p10 = &u10.x;
    const unsigned int* p11 = &u11.x;
#pragma unroll
    for (int k = 0; k < 4; ++k) {
      a[2 * k] = w00 * bflo(p00[k]) + w01 * bflo(p01[k]) + w10 * bflo(p10[k]) +
                 w11 * bflo(p11[k]);
      a[2 * k + 1] = w00 * bfhi(p00[k]) + w01 * bfhi(p01[k]) +
                     w10 * bfhi(p10[k]) + w11 * bfhi(p11[k]);
    }
  }

  // reduce-scatter over the 16 sample-groups (g = lane>>2; rounds flip
  // g bits 0,1,2 halving values/lane, then plain add across g bit3).
  const bool b0 = (lane >> 2) & 1;
  const bool b1 = (lane >> 3) & 1;
  const bool b2 = (lane >> 4) & 1;
#pragma unroll
  for (int rr = 0; rr < 2; ++rr) {
    float* v = rr ? acc1 : acc0;
#pragma unroll
    for (int jj = 0; jj < 4; ++jj) {
      float lo = v[jj], hi = v[jj + 4];
      float recv = __shfl_xor(b0 ? lo : hi, 4);
      v[jj] = (b0 ? hi : lo) + recv;
    }
#pragma unroll
    for (int jj = 0; jj < 2; ++jj) {
      float lo = v[jj], hi = v[jj + 2];
      float recv = __shfl_xor(b1 ? lo : hi, 8);
      v[jj] = (b1 ? hi : lo) + recv;
    }
    {
      float lo = v[0], hi = v[1];
      float recv = __shfl_xor(b2 ? lo : hi, 16);
      v[0] = (b2 ? hi : lo) + recv;
    }
    v[0] += __shfl_xor(v[0], 32);
  }

  // lane -> (row, dim): lanes 0..31 store row r0, 32..63 store r0+1.
  const int dim = d8 * 8 + (b0 ? 4 : 0) + (b1 ? 2 : 0) + (b2 ? 1 : 0);
  const int row = (lane < 32) ? r0 : (r0 + 1);
  const float val = (lane < 32) ? acc0[0] : acc1[0];
  sampledb[(size_t)row * EMB + h * 32 + dim] = bf16bits(val);
}

// ---------------------------------------------------------------------------
// K4: out = sampled @ W_out + b_out + query (residual fused).
// ---------------------------------------------------------------------------
__global__ __launch_bounds__(256, 2) void oproj_kernel(
    const unsigned short* __restrict__ sampledb,
    const unsigned short* __restrict__ Wt, const float* __restrict__ b_out,
    const float* __restrict__ query, float* __restrict__ out) {
  __shared__ unsigned short ldsA[128 * LDSTR];
  __shared__ unsigned short ldsB[128 * LDSTR];
  const int tid = threadIdx.x, lane = tid & 63, w = tid >> 6;
  const int wm = w >> 1, wn = w & 1;
  const int chunk = blockIdx.x >> 4, i = blockIdx.x & 15;
  const int m_idx = chunk * 8 + (i & 7);
  if (m_idx >= 188) return;
  const int m0 = m_idx * 128;
  const int n0 = (i >> 3) * 128;
  floatx4 acc[4][4];
  const floatx4 zero = {0.f, 0.f, 0.f, 0.f};
#pragma unroll
  for (int i2 = 0; i2 < 4; i2++)
#pragma unroll
    for (int j = 0; j < 4; j++) acc[i2][j] = zero;

  gemm_loop_bf16A(sampledb, MQ, m0, Wt, 256, n0, ldsA, ldsB, tid, wm, wn, lane,
                  acc);

  const int quad = lane >> 4, cl = lane & 15;
#pragma unroll
  for (int mt = 0; mt < 4; ++mt) {
#pragma unroll
    for (int r = 0; r < 4; ++r) {
      const int row = m0 + wm * 64 + mt * 16 + quad * 4 + r;
      if (row < MQ) {
#pragma unroll
        for (int nt = 0; nt < 4; ++nt) {
          const int c = n0 + wn * 64 + nt * 16 + cl;
          out[(size_t)row * EMB + c] =
              acc[mt][nt][r] + b_out[c] + query[(size_t)row * EMB + c];
        }
      }
    }
  }
}

// ---------------------------------------------------------------------------
extern "C" void kernel_launch(void* const* d_in, const int* in_sizes, int n_in,
                              void* d_out, int out_size, void* d_ws,
                              size_t ws_size, hipStream_t stream) {
  const float* query  = (const float*)d_in[0];
  const float* value  = (const float*)d_in[1];
  const float* refpts = (const float*)d_in[2];
  const float* W_off  = (const float*)d_in[3];
  const float* b_off  = (const float*)d_in[4];
  const float* W_attn = (const float*)d_in[5];
  const float* b_attn = (const float*)d_in[6];
  const float* W_val  = (const float*)d_in[7];
  const float* b_val  = (const float*)d_in[8];
  const float* W_out  = (const float*)d_in[9];
  const float* b_out  = (const float*)d_in[10];
  float* out = (float*)d_out;

  char* ws = (char*)d_ws;
  unsigned short* vbh = (unsigned short*)ws;                   // 27,226,112 B
  float* locbuf = (float*)(ws + 27226112);                     // 24,576,000 B
  float* awbuf = (float*)(ws + 51802112);                      // 12,288,000 B
  unsigned short* sampledb = (unsigned short*)(ws + 64090112); // 12,288,000 B
  unsigned short* Wt_val = (unsigned short*)(ws + 76378112);   //    131,072 B
  unsigned short* Wt_qcat = (unsigned short*)(ws + 76509184);  //    196,608 B
  unsigned short* Wt_out = (unsigned short*)(ws + 76705792);   //    131,072 B

  wtrans_kernel<<<896, 256, 0, stream>>>(W_val, W_off, W_attn, W_out, Wt_val,
                                         Wt_qcat, Wt_out);
  vqproj_kernel<<<1408, 256, 0, stream>>>(value, Wt_val, b_val, vbh, query,
                                          Wt_qcat, refpts, b_off, b_attn,
                                          locbuf, awbuf);
  sample_kernel<<<24000, 256, 0, stream>>>(vbh, locbuf, awbuf, sampledb);
  oproj_kernel<<<384, 256, 0, stream>>>(sampledb, Wt_out, b_out, query, out);
}